// Round 3
// baseline (707.242 us; speedup 1.0000x reference)
//
#include <hip/hip_runtime.h>

// Problem constants
#define BB    8
#define CFULL 512
#define CIN   256
#define CI    128
#define NTOT  4096   // views*t*v = 4*32*32
#define MM    1024   // views*(t/2)*(v/2)

// Workspace float offsets
#define F_TH    0u          // theta[b][n][i]      8*4096*128 = 4,194,304
#define F_PHIF  4194304u    // phi_full[b][i][n]   8*128*4096 = 4,194,304
#define F_PHIT  8388608u    // phiT[b][m][i]       8*1024*128 = 1,048,576
#define F_GF    9437184u    // g_full[b][d][n]     8*256*4096 = 8,388,608
#define F_GT    17825792u   // gT[b][d][m]         8*256*1024 = 2,097,152
#define F_YT    F_GF        // yT[b][d][n] aliases g_full (dead after pool_g)
// total ws: 19,922,944 floats = 79.7 MB

__device__ __forceinline__ float bflo(unsigned int u) {
  union { unsigned int i; float f; } x; x.i = u << 16; return x.f;
}
__device__ __forceinline__ float bfhi(unsigned int u) {
  union { unsigned int i; float f; } x; x.i = u & 0xffff0000u; return x.f;
}
__device__ __forceinline__ unsigned short f2bf(float f) {
  union { unsigned int i; float f; } x; x.f = f;
  unsigned int r = x.i + 0x7fffu + ((x.i >> 16) & 1u);
  return (unsigned short)(r >> 16);
}

// ---------------------------------------------------------------------------
// theta & phi projections: A = mean over 2 channel groups (fused), K=256.
// block: 64 n x 128 o tile. blockIdx: (n-tile, ot[0=theta,1=phi], b)
// ---------------------------------------------------------------------------
__global__ __launch_bounds__(256)
void k_gemm_proj(const float* __restrict__ x,
                 const float* __restrict__ tw, const float* __restrict__ tb,
                 const float* __restrict__ pw, const float* __restrict__ pb,
                 float* __restrict__ ws) {
  const int nt = blockIdx.x, ot = blockIdx.y, b = blockIdx.z;
  const int n0 = nt * 64;
  const int tid = threadIdx.x;
  const int tx = tid & 15, ty = tid >> 4;
  const float* w    = ot ? pw : tw;
  const float* bias = ot ? pb : tb;

  __shared__ float a_s[16][68];
  __shared__ float w_s[16][128];

  float acc[4][8];
#pragma unroll
  for (int i = 0; i < 4; ++i)
#pragma unroll
    for (int j = 0; j < 8; ++j) acc[i][j] = 0.f;

  const int lkk = tid >> 4;          // 0..15 (A-load row)
  const int lnn = (tid & 15) * 4;    // A-load col
  const int lo  = tid & 127;         // W-load o
  const int lkb = (tid >> 7) * 8;    // W-load k base

  for (int kc = 0; kc < 256; kc += 16) {
    // A tile: mean over groups
    const float* xs = x + ((size_t)(b * 512 + 2 * (kc + lkk))) * 4096 + n0 + lnn;
    float4 xa = *(const float4*)xs;
    float4 xb = *(const float4*)(xs + 4096);
    float4 av = make_float4(0.5f * (xa.x + xb.x), 0.5f * (xa.y + xb.y),
                            0.5f * (xa.z + xb.z), 0.5f * (xa.w + xb.w));
    *(float4*)&a_s[lkk][lnn] = av;
    // W tile (transposed into [k][o])
    const float* wp = w + (size_t)lo * 256 + kc + lkb;
    float4 w0 = *(const float4*)wp;
    float4 w1 = *(const float4*)(wp + 4);
    w_s[lkb + 0][lo] = w0.x; w_s[lkb + 1][lo] = w0.y;
    w_s[lkb + 2][lo] = w0.z; w_s[lkb + 3][lo] = w0.w;
    w_s[lkb + 4][lo] = w1.x; w_s[lkb + 5][lo] = w1.y;
    w_s[lkb + 6][lo] = w1.z; w_s[lkb + 7][lo] = w1.w;
    __syncthreads();
#pragma unroll
    for (int kk = 0; kk < 16; ++kk) {
      const float4 a4 = *(const float4*)&a_s[kk][4 * tx];
      const float4 b0 = *(const float4*)&w_s[kk][8 * ty];
      const float4 b1 = *(const float4*)&w_s[kk][8 * ty + 4];
      const float ar[4] = {a4.x, a4.y, a4.z, a4.w};
      const float br[8] = {b0.x, b0.y, b0.z, b0.w, b1.x, b1.y, b1.z, b1.w};
#pragma unroll
      for (int i = 0; i < 4; ++i)
#pragma unroll
        for (int j = 0; j < 8; ++j) acc[i][j] += ar[i] * br[j];
    }
    __syncthreads();
  }

  float bs[8];
#pragma unroll
  for (int j = 0; j < 8; ++j) bs[j] = bias[8 * ty + j];

  if (ot == 0) {
    float* th = ws + F_TH;
#pragma unroll
    for (int i = 0; i < 4; ++i) {
      float* dst = th + ((size_t)(b * 4096 + n0 + 4 * tx + i)) * 128 + 8 * ty;
      *(float4*)dst       = make_float4(acc[i][0] + bs[0], acc[i][1] + bs[1],
                                        acc[i][2] + bs[2], acc[i][3] + bs[3]);
      *(float4*)(dst + 4) = make_float4(acc[i][4] + bs[4], acc[i][5] + bs[5],
                                        acc[i][6] + bs[6], acc[i][7] + bs[7]);
    }
  } else {
    float* ph = ws + F_PHIF;
#pragma unroll
    for (int j = 0; j < 8; ++j) {
      float* dst = ph + ((size_t)(b * 128 + 8 * ty + j)) * 4096 + n0 + 4 * tx;
      *(float4*)dst = make_float4(acc[0][j] + bs[j], acc[1][j] + bs[j],
                                  acc[2][j] + bs[j], acc[3][j] + bs[j]);
    }
  }
}

// ---------------------------------------------------------------------------
// g projection (per channel-group), K=256. blockIdx: (n-tile, group, b)
// ---------------------------------------------------------------------------
__global__ __launch_bounds__(256)
void k_gemm_g(const float* __restrict__ x,
              const float* __restrict__ gw, const float* __restrict__ gb,
              float* __restrict__ ws) {
  const int nt = blockIdx.x, gr = blockIdx.y, b = blockIdx.z;
  const int n0 = nt * 64;
  const int tid = threadIdx.x;
  const int tx = tid & 15, ty = tid >> 4;

  __shared__ float a_s[16][68];
  __shared__ float w_s[16][128];

  float acc[4][8];
#pragma unroll
  for (int i = 0; i < 4; ++i)
#pragma unroll
    for (int j = 0; j < 8; ++j) acc[i][j] = 0.f;

  const int lkk = tid >> 4;
  const int lnn = (tid & 15) * 4;
  const int lo  = tid & 127;
  const int lkb = (tid >> 7) * 8;

  for (int kc = 0; kc < 256; kc += 16) {
    const float* xs = x + ((size_t)(b * 512 + 2 * (kc + lkk) + gr)) * 4096 + n0 + lnn;
    *(float4*)&a_s[lkk][lnn] = *(const float4*)xs;
    const float* wp = gw + (size_t)lo * 256 + kc + lkb;
    float4 w0 = *(const float4*)wp;
    float4 w1 = *(const float4*)(wp + 4);
    w_s[lkb + 0][lo] = w0.x; w_s[lkb + 1][lo] = w0.y;
    w_s[lkb + 2][lo] = w0.z; w_s[lkb + 3][lo] = w0.w;
    w_s[lkb + 4][lo] = w1.x; w_s[lkb + 5][lo] = w1.y;
    w_s[lkb + 6][lo] = w1.z; w_s[lkb + 7][lo] = w1.w;
    __syncthreads();
#pragma unroll
    for (int kk = 0; kk < 16; ++kk) {
      const float4 a4 = *(const float4*)&a_s[kk][4 * tx];
      const float4 b0 = *(const float4*)&w_s[kk][8 * ty];
      const float4 b1 = *(const float4*)&w_s[kk][8 * ty + 4];
      const float ar[4] = {a4.x, a4.y, a4.z, a4.w};
      const float br[8] = {b0.x, b0.y, b0.z, b0.w, b1.x, b1.y, b1.z, b1.w};
#pragma unroll
      for (int i = 0; i < 4; ++i)
#pragma unroll
        for (int j = 0; j < 8; ++j) acc[i][j] += ar[i] * br[j];
    }
    __syncthreads();
  }

  float bs[8];
#pragma unroll
  for (int j = 0; j < 8; ++j) bs[j] = gb[8 * ty + j];

  float* gf = ws + F_GF;
#pragma unroll
  for (int j = 0; j < 8; ++j) {
    const int d = (8 * ty + j) * 2 + gr;
    float* dst = gf + ((size_t)(b * 256 + d)) * 4096 + n0 + 4 * tx;
    *(float4*)dst = make_float4(acc[0][j] + bs[j], acc[1][j] + bs[j],
                                acc[2][j] + bs[j], acc[3][j] + bs[j]);
  }
}

// ---------------------------------------------------------------------------
// (1,2,2) max-pools.  m = vw*256 + tp*16 + vp ; nbase = vw*1024 + tp*64 + 2*vp
// ---------------------------------------------------------------------------
__global__ __launch_bounds__(256)
void k_pool_phi(float* __restrict__ ws) {
  const int idx = blockIdx.x * 256 + threadIdx.x;   // 8*128*1024
  const int b = idx >> 17;
  const int rem = idx & 131071;
  const int i = rem >> 10;
  const int m = rem & 1023;
  const int vw = m >> 8, tp = (m >> 4) & 15, vp = m & 15;
  const int nb = vw * 1024 + tp * 64 + 2 * vp;
  const float* src = ws + F_PHIF + ((size_t)(b * 128 + i)) * 4096 + nb;
  const float v = fmaxf(fmaxf(src[0], src[1]), fmaxf(src[32], src[33]));
  ws[F_PHIT + ((size_t)(b * 1024 + m)) * 128 + i] = v;
}

__global__ __launch_bounds__(256)
void k_pool_g(float* __restrict__ ws) {
  const int idx = blockIdx.x * 256 + threadIdx.x;   // 8*256*1024
  const int b = idx >> 18;
  const int rem = idx & 262143;
  const int d = rem >> 10;
  const int m = rem & 1023;
  const int vw = m >> 8, tp = (m >> 4) & 15, vp = m & 15;
  const int nb = vw * 1024 + tp * 64 + 2 * vp;
  const float* src = ws + F_GF + ((size_t)(b * 256 + d)) * 4096 + nb;
  const float v = fmaxf(fmaxf(src[0], src[1]), fmaxf(src[32], src[33]));
  ws[F_GT + ((size_t)(b * 256 + d)) * 1024 + m] = v;
}

// ---------------------------------------------------------------------------
// Flash attention: per block 64 n-rows of one batch; m-tiles of 32.
// thread: rq = tid>>4 (rows 4rq..4rq+3), dq = tid&15.
//   S ownership: m = 2dq..2dq+1 ; PV ownership: d = 64c + 4dq + e.
// ---------------------------------------------------------------------------
__global__ __launch_bounds__(256)
void k_attn(float* __restrict__ ws) {
  const int b = blockIdx.y;
  const int n0 = blockIdx.x * 64;
  const int tid = threadIdx.x;
  const int rq = tid >> 4;
  const int dq = tid & 15;

  __shared__ float smemf[14720];                       // 58,880 B
  unsigned int* th2 = (unsigned int*)smemf;            // [64][66] bf16x2
  float* phis = smemf + 4224;                          // [32][132]
  unsigned short* gs = (unsigned short*)(smemf + 8448);// [32][256] bf16
  float* ps = smemf + 12544;                           // [64][34]
  float* tr = smemf + 4224;                            // [64][65] alias of phis

  const float* theta = ws + F_TH;
  const float* phiT  = ws + F_PHIT;
  const float* gT    = ws + F_GT;
  float* yT = ws + F_YT;

  // stage theta tile (64 x 128) as packed bf16
  {
    const int r = tid >> 2, i0 = (tid & 3) * 32;
    const float* src = theta + ((size_t)(b * 4096 + n0 + r)) * 128 + i0;
    unsigned int* dst = th2 + r * 66 + (i0 >> 1);
#pragma unroll
    for (int q = 0; q < 8; ++q) {
      float4 v = *(const float4*)(src + 4 * q);
      dst[2 * q]     = (unsigned int)f2bf(v.x) | ((unsigned int)f2bf(v.y) << 16);
      dst[2 * q + 1] = (unsigned int)f2bf(v.z) | ((unsigned int)f2bf(v.w) << 16);
    }
  }

  float acc[4][4][4];
#pragma unroll
  for (int rr = 0; rr < 4; ++rr)
#pragma unroll
    for (int c = 0; c < 4; ++c)
#pragma unroll
      for (int e = 0; e < 4; ++e) acc[rr][c][e] = 0.f;
  float mrun[4], lsum[4];
#pragma unroll
  for (int rr = 0; rr < 4; ++rr) { mrun[rr] = -1e30f; lsum[rr] = 0.f; }

  for (int mt = 0; mt < 32; ++mt) {
    __syncthreads();
    // stage phi tile [32 m][128 i]
    {
      const int mm = tid >> 3, ic = (tid & 7) * 16;
      const float* src = phiT + ((size_t)(b * 1024 + mt * 32 + mm)) * 128 + ic;
      float* dst = phis + mm * 132 + ic;
#pragma unroll
      for (int q = 0; q < 4; ++q)
        *(float4*)(dst + 4 * q) = *(const float4*)(src + 4 * q);
    }
    // stage g tile [32 m][256 d] as bf16
    {
      const float* src = gT + ((size_t)(b * 256 + tid)) * 1024 + mt * 32;
#pragma unroll
      for (int q = 0; q < 8; ++q) {
        float4 v = *(const float4*)(src + 4 * q);
        gs[(4 * q + 0) * 256 + tid] = f2bf(v.x);
        gs[(4 * q + 1) * 256 + tid] = f2bf(v.y);
        gs[(4 * q + 2) * 256 + tid] = f2bf(v.z);
        gs[(4 * q + 3) * 256 + tid] = f2bf(v.w);
      }
    }
    __syncthreads();

    // S = theta . phi^T  (4 rows x 2 m per thread)
    float s[4][2];
#pragma unroll
    for (int rr = 0; rr < 4; ++rr) { s[rr][0] = 0.f; s[rr][1] = 0.f; }
    const float* ph0 = phis + (2 * dq) * 132;
    const float* ph1 = phis + (2 * dq + 1) * 132;
    for (int i2 = 0; i2 < 64; ++i2) {
      const float2 p0 = *(const float2*)(ph0 + 2 * i2);
      const float2 p1 = *(const float2*)(ph1 + 2 * i2);
#pragma unroll
      for (int rr = 0; rr < 4; ++rr) {
        const unsigned int t2 = th2[(4 * rq + rr) * 66 + i2];
        const float ta = bflo(t2), tb2 = bfhi(t2);
        s[rr][0] += ta * p0.x + tb2 * p0.y;
        s[rr][1] += ta * p1.x + tb2 * p1.y;
      }
    }

    // online softmax update (row reduce across the 16 dq lanes)
#pragma unroll
    for (int rr = 0; rr < 4; ++rr) {
      float tmax = fmaxf(s[rr][0], s[rr][1]);
      tmax = fmaxf(tmax, __shfl_xor(tmax, 1));
      tmax = fmaxf(tmax, __shfl_xor(tmax, 2));
      tmax = fmaxf(tmax, __shfl_xor(tmax, 4));
      tmax = fmaxf(tmax, __shfl_xor(tmax, 8));
      const float mnew = fmaxf(mrun[rr], tmax);
      const float scl = __expf(mrun[rr] - mnew);
      mrun[rr] = mnew;
      const float p0 = __expf(s[rr][0] - mnew);
      const float p1 = __expf(s[rr][1] - mnew);
      float rs = p0 + p1;
      rs += __shfl_xor(rs, 1);
      rs += __shfl_xor(rs, 2);
      rs += __shfl_xor(rs, 4);
      rs += __shfl_xor(rs, 8);
      lsum[rr] = lsum[rr] * scl + rs;
      ps[(4 * rq + rr) * 34 + 2 * dq]     = p0;
      ps[(4 * rq + rr) * 34 + 2 * dq + 1] = p1;
#pragma unroll
      for (int c = 0; c < 4; ++c)
#pragma unroll
        for (int e = 0; e < 4; ++e) acc[rr][c][e] *= scl;
    }
    __syncthreads();

    // PV accumulate
    const unsigned int* gsu = (const unsigned int*)gs;
    for (int j = 0; j < 32; ++j) {
      float pj[4];
#pragma unroll
      for (int rr = 0; rr < 4; ++rr) pj[rr] = ps[(4 * rq + rr) * 34 + j];
#pragma unroll
      for (int c = 0; c < 4; ++c) {
        const unsigned int u0 = gsu[j * 128 + 32 * c + 2 * dq];
        const unsigned int u1 = gsu[j * 128 + 32 * c + 2 * dq + 1];
        const float g0 = bflo(u0), g1 = bfhi(u0), g2 = bflo(u1), g3 = bfhi(u1);
#pragma unroll
        for (int rr = 0; rr < 4; ++rr) {
          acc[rr][c][0] += pj[rr] * g0;
          acc[rr][c][1] += pj[rr] * g1;
          acc[rr][c][2] += pj[rr] * g2;
          acc[rr][c][3] += pj[rr] * g3;
        }
      }
    }
  }

  // normalize + LDS transpose + coalesced store of yT[d][n]
  float inv[4];
#pragma unroll
  for (int rr = 0; rr < 4; ++rr) inv[rr] = 1.0f / lsum[rr];
  const int dloc = tid >> 2, nch = (tid & 3) * 16;
#pragma unroll
  for (int c = 0; c < 4; ++c) {
    __syncthreads();
#pragma unroll
    for (int e = 0; e < 4; ++e)
#pragma unroll
      for (int rr = 0; rr < 4; ++rr)
        tr[(4 * dq + e) * 65 + 4 * rq + rr] = acc[rr][c][e] * inv[rr];
    __syncthreads();
    float* dst = yT + ((size_t)(b * 256 + 64 * c + dloc)) * 4096 + n0 + nch;
    const float* sr = tr + dloc * 65 + nch;
#pragma unroll
    for (int q = 0; q < 4; ++q)
      *(float4*)(dst + 4 * q) = make_float4(sr[4 * q], sr[4 * q + 1],
                                            sr[4 * q + 2], sr[4 * q + 3]);
  }
}

// ---------------------------------------------------------------------------
// Final W conv + bias + residual. K=128. blockIdx: (n-tile, gq[ot*2+gr], b)
// out[b][o*2+gr][n] = sum_i W_w[o][i]*yT[2i+gr][n] + W_b[o] + x[...]
// ---------------------------------------------------------------------------
__global__ __launch_bounds__(256)
void k_gemm_final(const float* __restrict__ x,
                  const float* __restrict__ Ww, const float* __restrict__ Wb,
                  const float* __restrict__ ws, float* __restrict__ out) {
  const int nt = blockIdx.x, gq = blockIdx.y, b = blockIdx.z;
  const int gr = gq & 1, ob = (gq >> 1) * 128;
  const int n0 = nt * 64;
  const int tid = threadIdx.x;
  const int tx = tid & 15, ty = tid >> 4;

  __shared__ float a_s[16][68];
  __shared__ float w_s[16][128];

  float acc[4][8];
#pragma unroll
  for (int i = 0; i < 4; ++i)
#pragma unroll
    for (int j = 0; j < 8; ++j) acc[i][j] = 0.f;

  const int lkk = tid >> 4;
  const int lnn = (tid & 15) * 4;
  const int lo  = tid & 127;
  const int lkb = (tid >> 7) * 8;

  for (int kc = 0; kc < 128; kc += 16) {
    const float* ys = ws + F_YT + ((size_t)(b * 256 + 2 * (kc + lkk) + gr)) * 4096 + n0 + lnn;
    *(float4*)&a_s[lkk][lnn] = *(const float4*)ys;
    const float* wp = Ww + (size_t)(ob + lo) * 128 + kc + lkb;
    float4 w0 = *(const float4*)wp;
    float4 w1 = *(const float4*)(wp + 4);
    w_s[lkb + 0][lo] = w0.x; w_s[lkb + 1][lo] = w0.y;
    w_s[lkb + 2][lo] = w0.z; w_s[lkb + 3][lo] = w0.w;
    w_s[lkb + 4][lo] = w1.x; w_s[lkb + 5][lo] = w1.y;
    w_s[lkb + 6][lo] = w1.z; w_s[lkb + 7][lo] = w1.w;
    __syncthreads();
#pragma unroll
    for (int kk = 0; kk < 16; ++kk) {
      const float4 a4 = *(const float4*)&a_s[kk][4 * tx];
      const float4 b0 = *(const float4*)&w_s[kk][8 * ty];
      const float4 b1 = *(const float4*)&w_s[kk][8 * ty + 4];
      const float ar[4] = {a4.x, a4.y, a4.z, a4.w};
      const float br[8] = {b0.x, b0.y, b0.z, b0.w, b1.x, b1.y, b1.z, b1.w};
#pragma unroll
      for (int i = 0; i < 4; ++i)
#pragma unroll
        for (int j = 0; j < 8; ++j) acc[i][j] += ar[i] * br[j];
    }
    __syncthreads();
  }

  float bs[8];
#pragma unroll
  for (int j = 0; j < 8; ++j) bs[j] = Wb[ob + 8 * ty + j];

#pragma unroll
  for (int j = 0; j < 8; ++j) {
    const int o = ob + 8 * ty + j;
    const int ch = o * 2 + gr;
    const size_t off = ((size_t)(b * 512 + ch)) * 4096 + n0 + 4 * tx;
    const float4 xv = *(const float4*)(x + off);
    *(float4*)(out + off) = make_float4(acc[0][j] + bs[j] + xv.x,
                                        acc[1][j] + bs[j] + xv.y,
                                        acc[2][j] + bs[j] + xv.z,
                                        acc[3][j] + bs[j] + xv.w);
  }
}

extern "C" void kernel_launch(void* const* d_in, const int* in_sizes, int n_in,
                              void* d_out, int out_size, void* d_ws, size_t ws_size,
                              hipStream_t stream) {
  const float* x  = (const float*)d_in[0];
  const float* gw = (const float*)d_in[1];
  const float* gb = (const float*)d_in[2];
  const float* tw = (const float*)d_in[3];
  const float* tb = (const float*)d_in[4];
  const float* pw = (const float*)d_in[5];
  const float* pb = (const float*)d_in[6];
  const float* Ww = (const float*)d_in[7];
  const float* Wb = (const float*)d_in[8];
  float* out = (float*)d_out;
  float* ws  = (float*)d_ws;

  k_gemm_proj<<<dim3(64, 2, 8), 256, 0, stream>>>(x, tw, tb, pw, pb, ws);
  k_gemm_g<<<dim3(64, 2, 8), 256, 0, stream>>>(x, gw, gb, ws);
  k_pool_phi<<<4096, 256, 0, stream>>>(ws);
  k_pool_g<<<8192, 256, 0, stream>>>(ws);
  k_attn<<<dim3(64, 8), 256, 0, stream>>>(ws);
  k_gemm_final<<<dim3(64, 4, 8), 256, 0, stream>>>(x, Ww, Wb, ws, out);
}

// Round 4
// 276.022 us; speedup vs baseline: 2.5623x; 2.5623x over previous
//
#include <hip/hip_runtime.h>

// Problem constants
#define BB    8
#define CFULL 512
#define CIN   256
#define CI    128
#define NTOT  4096   // views*t*v = 4*32*32
#define MM    1024   // views*(t/2)*(v/2)

// Workspace float offsets
#define F_THB   0u          // theta bf16 [8][4096][128]  -> 2,097,152 f
#define F_PHIF  2097152u    // phi_full f32 [8][128][4096]-> 4,194,304 f
#define F_GF    6291456u    // g_full f32 [8][256][4096]  -> 8,388,608 f
#define F_YT    F_GF        // yT f32 [8][256][4096] aliases g_full (dead after pool)
#define F_PHIB  14680064u   // phi bf16 [8][1024][128]    ->   524,288 f
#define F_GB    15204352u   // g bf16 [8][256][1024]      -> 1,048,576 f
// total ws: 16,252,928 floats = 65.0 MB

typedef __attribute__((ext_vector_type(4))) float f32x4;
typedef __attribute__((ext_vector_type(8))) short bf16x8;

__device__ __forceinline__ unsigned short f2bf(float f) {
  union { unsigned int i; float f; } x; x.f = f;
  unsigned int r = x.i + 0x7fffu + ((x.i >> 16) & 1u);
  return (unsigned short)(r >> 16);
}

// ---------------------------------------------------------------------------
// theta & phi projections: A = mean over 2 channel groups (fused), K=256.
// theta -> bf16 [b][n][i]; phi -> f32 [b][i][n] (pooled later).
// ---------------------------------------------------------------------------
__global__ __launch_bounds__(256)
void k_gemm_proj(const float* __restrict__ x,
                 const float* __restrict__ tw, const float* __restrict__ tb,
                 const float* __restrict__ pw, const float* __restrict__ pb,
                 float* __restrict__ ws) {
  const int nt = blockIdx.x, ot = blockIdx.y, b = blockIdx.z;
  const int n0 = nt * 64;
  const int tid = threadIdx.x;
  const int tx = tid & 15, ty = tid >> 4;
  const float* w    = ot ? pw : tw;
  const float* bias = ot ? pb : tb;

  __shared__ float a_s[16][68];
  __shared__ float w_s[16][128];

  float acc[4][8];
#pragma unroll
  for (int i = 0; i < 4; ++i)
#pragma unroll
    for (int j = 0; j < 8; ++j) acc[i][j] = 0.f;

  const int lkk = tid >> 4;
  const int lnn = (tid & 15) * 4;
  const int lo  = tid & 127;
  const int lkb = (tid >> 7) * 8;

  for (int kc = 0; kc < 256; kc += 16) {
    const float* xs = x + ((size_t)(b * 512 + 2 * (kc + lkk))) * 4096 + n0 + lnn;
    float4 xa = *(const float4*)xs;
    float4 xb = *(const float4*)(xs + 4096);
    float4 av = make_float4(0.5f * (xa.x + xb.x), 0.5f * (xa.y + xb.y),
                            0.5f * (xa.z + xb.z), 0.5f * (xa.w + xb.w));
    *(float4*)&a_s[lkk][lnn] = av;
    const float* wp = w + (size_t)lo * 256 + kc + lkb;
    float4 w0 = *(const float4*)wp;
    float4 w1 = *(const float4*)(wp + 4);
    w_s[lkb + 0][lo] = w0.x; w_s[lkb + 1][lo] = w0.y;
    w_s[lkb + 2][lo] = w0.z; w_s[lkb + 3][lo] = w0.w;
    w_s[lkb + 4][lo] = w1.x; w_s[lkb + 5][lo] = w1.y;
    w_s[lkb + 6][lo] = w1.z; w_s[lkb + 7][lo] = w1.w;
    __syncthreads();
#pragma unroll
    for (int kk = 0; kk < 16; ++kk) {
      const float4 a4 = *(const float4*)&a_s[kk][4 * tx];
      const float4 b0 = *(const float4*)&w_s[kk][8 * ty];
      const float4 b1 = *(const float4*)&w_s[kk][8 * ty + 4];
      const float ar[4] = {a4.x, a4.y, a4.z, a4.w};
      const float br[8] = {b0.x, b0.y, b0.z, b0.w, b1.x, b1.y, b1.z, b1.w};
#pragma unroll
      for (int i = 0; i < 4; ++i)
#pragma unroll
        for (int j = 0; j < 8; ++j) acc[i][j] += ar[i] * br[j];
    }
    __syncthreads();
  }

  float bs[8];
#pragma unroll
  for (int j = 0; j < 8; ++j) bs[j] = bias[8 * ty + j];

  if (ot == 0) {
    unsigned short* th = (unsigned short*)(ws + F_THB);
#pragma unroll
    for (int i = 0; i < 4; ++i) {
      unsigned short* dst = th + ((size_t)(b * 4096 + n0 + 4 * tx + i)) * 128 + 8 * ty;
      unsigned int u0 = (unsigned int)f2bf(acc[i][0] + bs[0]) |
                        ((unsigned int)f2bf(acc[i][1] + bs[1]) << 16);
      unsigned int u1 = (unsigned int)f2bf(acc[i][2] + bs[2]) |
                        ((unsigned int)f2bf(acc[i][3] + bs[3]) << 16);
      unsigned int u2 = (unsigned int)f2bf(acc[i][4] + bs[4]) |
                        ((unsigned int)f2bf(acc[i][5] + bs[5]) << 16);
      unsigned int u3 = (unsigned int)f2bf(acc[i][6] + bs[6]) |
                        ((unsigned int)f2bf(acc[i][7] + bs[7]) << 16);
      *(uint4*)dst = make_uint4(u0, u1, u2, u3);
    }
  } else {
    float* ph = ws + F_PHIF;
#pragma unroll
    for (int j = 0; j < 8; ++j) {
      float* dst = ph + ((size_t)(b * 128 + 8 * ty + j)) * 4096 + n0 + 4 * tx;
      *(float4*)dst = make_float4(acc[0][j] + bs[j], acc[1][j] + bs[j],
                                  acc[2][j] + bs[j], acc[3][j] + bs[j]);
    }
  }
}

// ---------------------------------------------------------------------------
// g projection (per channel-group), K=256 -> g_full f32 [b][d][n]
// ---------------------------------------------------------------------------
__global__ __launch_bounds__(256)
void k_gemm_g(const float* __restrict__ x,
              const float* __restrict__ gw, const float* __restrict__ gb,
              float* __restrict__ ws) {
  const int nt = blockIdx.x, gr = blockIdx.y, b = blockIdx.z;
  const int n0 = nt * 64;
  const int tid = threadIdx.x;
  const int tx = tid & 15, ty = tid >> 4;

  __shared__ float a_s[16][68];
  __shared__ float w_s[16][128];

  float acc[4][8];
#pragma unroll
  for (int i = 0; i < 4; ++i)
#pragma unroll
    for (int j = 0; j < 8; ++j) acc[i][j] = 0.f;

  const int lkk = tid >> 4;
  const int lnn = (tid & 15) * 4;
  const int lo  = tid & 127;
  const int lkb = (tid >> 7) * 8;

  for (int kc = 0; kc < 256; kc += 16) {
    const float* xs = x + ((size_t)(b * 512 + 2 * (kc + lkk) + gr)) * 4096 + n0 + lnn;
    *(float4*)&a_s[lkk][lnn] = *(const float4*)xs;
    const float* wp = gw + (size_t)lo * 256 + kc + lkb;
    float4 w0 = *(const float4*)wp;
    float4 w1 = *(const float4*)(wp + 4);
    w_s[lkb + 0][lo] = w0.x; w_s[lkb + 1][lo] = w0.y;
    w_s[lkb + 2][lo] = w0.z; w_s[lkb + 3][lo] = w0.w;
    w_s[lkb + 4][lo] = w1.x; w_s[lkb + 5][lo] = w1.y;
    w_s[lkb + 6][lo] = w1.z; w_s[lkb + 7][lo] = w1.w;
    __syncthreads();
#pragma unroll
    for (int kk = 0; kk < 16; ++kk) {
      const float4 a4 = *(const float4*)&a_s[kk][4 * tx];
      const float4 b0 = *(const float4*)&w_s[kk][8 * ty];
      const float4 b1 = *(const float4*)&w_s[kk][8 * ty + 4];
      const float ar[4] = {a4.x, a4.y, a4.z, a4.w};
      const float br[8] = {b0.x, b0.y, b0.z, b0.w, b1.x, b1.y, b1.z, b1.w};
#pragma unroll
      for (int i = 0; i < 4; ++i)
#pragma unroll
        for (int j = 0; j < 8; ++j) acc[i][j] += ar[i] * br[j];
    }
    __syncthreads();
  }

  float bs[8];
#pragma unroll
  for (int j = 0; j < 8; ++j) bs[j] = gb[8 * ty + j];

  float* gf = ws + F_GF;
#pragma unroll
  for (int j = 0; j < 8; ++j) {
    const int d = (8 * ty + j) * 2 + gr;
    float* dst = gf + ((size_t)(b * 256 + d)) * 4096 + n0 + 4 * tx;
    *(float4*)dst = make_float4(acc[0][j] + bs[j], acc[1][j] + bs[j],
                                acc[2][j] + bs[j], acc[3][j] + bs[j]);
  }
}

// ---------------------------------------------------------------------------
// (1,2,2) max-pools. m = vw*256 + tp*16 + vp ; nbase = vw*1024 + tp*64 + 2*vp
// phi -> bf16 [b][m][128] ; g -> bf16 [b][d][1024]
// ---------------------------------------------------------------------------
__global__ __launch_bounds__(256)
void k_pool_phi(float* __restrict__ ws) {
  const int idx = blockIdx.x * 256 + threadIdx.x;   // 8*128*1024
  const int b = idx >> 17;
  const int rem = idx & 131071;
  const int i = rem >> 10;
  const int m = rem & 1023;
  const int vw = m >> 8, tp = (m >> 4) & 15, vp = m & 15;
  const int nb = vw * 1024 + tp * 64 + 2 * vp;
  const float* src = ws + F_PHIF + ((size_t)(b * 128 + i)) * 4096 + nb;
  const float v = fmaxf(fmaxf(src[0], src[1]), fmaxf(src[32], src[33]));
  unsigned short* dst = (unsigned short*)(ws + F_PHIB);
  dst[((size_t)(b * 1024 + m)) * 128 + i] = f2bf(v);
}

__global__ __launch_bounds__(256)
void k_pool_g(float* __restrict__ ws) {
  const int idx = blockIdx.x * 256 + threadIdx.x;   // 8*256*1024
  const int b = idx >> 18;
  const int rem = idx & 262143;
  const int d = rem >> 10;
  const int m = rem & 1023;
  const int vw = m >> 8, tp = (m >> 4) & 15, vp = m & 15;
  const int nb = vw * 1024 + tp * 64 + 2 * vp;
  const float* src = ws + F_GF + ((size_t)(b * 256 + d)) * 4096 + nb;
  const float v = fmaxf(fmaxf(src[0], src[1]), fmaxf(src[32], src[33]));
  unsigned short* dst = (unsigned short*)(ws + F_GB);
  dst[((size_t)(b * 256 + d)) * 1024 + m] = f2bf(v);
}

// ---------------------------------------------------------------------------
// MFMA flash attention. Block = 64 n-rows of one batch, 4 waves, m-tiles of 64.
// Swapped QK^T: S^T = mfma(K, Q) -> lane holds P[n=col][m=16s+4q+r]: softmax
// is lane-local + shfl_xor(16/32). O^T = mfma(V^T, P^T) -> [d][n] = yT layout.
// All LDS tiles byte-XOR swizzled by ((row&7)<<4) for conflict-free b128.
// ---------------------------------------------------------------------------
__global__ __launch_bounds__(256)
void k_attn_mfma(float* __restrict__ ws) {
  const int b = blockIdx.y;
  const int n0 = blockIdx.x * 64;
  const int tid = threadIdx.x;
  const int w = tid >> 6;
  const int lane = tid & 63;
  const int q = lane >> 4;
  const int col = lane & 15;
  const int ksw = (col & 7) << 4;

  __shared__ unsigned short kt[64 * 128];   // K tile [m][i]   16,384 B
  __shared__ unsigned short vt[256 * 64];   // V^T tile [d][m] 32,768 B
  __shared__ unsigned short pl[4 * 16 * 64];// per-wave P       8,192 B

  const unsigned short* thetaB = (const unsigned short*)(ws + F_THB);
  const unsigned short* phiB   = (const unsigned short*)(ws + F_PHIB);
  const unsigned short* gB     = (const unsigned short*)(ws + F_GB);
  float* yT = ws + F_YT;

  // Q fragments (B-operand): qf[c] = theta[n0+16w+col][32c+8q .. +8]
  bf16x8 qf[4];
  {
    const unsigned short* qp = thetaB + ((size_t)(b * 4096 + n0 + 16 * w + col)) * 128 + 8 * q;
#pragma unroll
    for (int c = 0; c < 4; ++c)
      qf[c] = *(const bf16x8*)(qp + 32 * c);
  }

  f32x4 ot[16];
#pragma unroll
  for (int t = 0; t < 16; ++t) ot[t] = (f32x4){0.f, 0.f, 0.f, 0.f};
  float mrun = -1e30f, lsum = 0.f;

  char* plw = (char*)pl + w * 2048;

  for (int mt = 0; mt < 16; ++mt) {
    const int m0 = mt * 64;
    __syncthreads();
    // stage K tile [64][128] bf16 (XOR swizzled)
    {
      const int r = tid >> 2;
      const unsigned short* src = phiB + ((size_t)(b * 1024 + m0 + r)) * 128 + (tid & 3) * 32;
      char* drow = (char*)kt + r * 256;
      const int sw = (r & 7) << 4;
      const int b0 = (tid & 3) * 64;
#pragma unroll
      for (int k = 0; k < 4; ++k)
        *(uint4*)(drow + ((b0 + 16 * k) ^ sw)) = *(const uint4*)(src + 8 * k);
    }
    // stage V^T tile [256 d][64 m] bf16 (XOR swizzled)
    {
      const unsigned short* src = gB + ((size_t)(b * 256 + tid)) * 1024 + m0;
      char* drow = (char*)vt + tid * 128;
      const int sw = (tid & 7) << 4;
#pragma unroll
      for (int k = 0; k < 8; ++k)
        *(uint4*)(drow + ((16 * k) ^ sw)) = *(const uint4*)(src + 8 * k);
    }
    __syncthreads();

    // S^T = K . Q^T  (st[s] covers m-local 16s..16s+15, n-local = col)
    f32x4 st[4];
#pragma unroll
    for (int s = 0; s < 4; ++s) st[s] = (f32x4){0.f, 0.f, 0.f, 0.f};
#pragma unroll
    for (int c = 0; c < 4; ++c) {
#pragma unroll
      for (int s = 0; s < 4; ++s) {
        const bf16x8 kf = *(const bf16x8*)((const char*)kt + (16 * s + col) * 256 +
                                           ((64 * c + 16 * q) ^ ksw));
        st[s] = __builtin_amdgcn_mfma_f32_16x16x32_bf16(kf, qf[c], st[s], 0, 0, 0);
      }
    }

    // online softmax: row n = (own) col; reduce over the 4 q-lanes
    float pmax = -1e30f;
#pragma unroll
    for (int s = 0; s < 4; ++s)
#pragma unroll
      for (int r = 0; r < 4; ++r) pmax = fmaxf(pmax, st[s][r]);
    pmax = fmaxf(pmax, __shfl_xor(pmax, 16));
    pmax = fmaxf(pmax, __shfl_xor(pmax, 32));
    const float mnew = fmaxf(mrun, pmax);
    const float scl = __expf(mrun - mnew);
    mrun = mnew;
    float p[4][4];
    float rsum = 0.f;
#pragma unroll
    for (int s = 0; s < 4; ++s)
#pragma unroll
      for (int r = 0; r < 4; ++r) {
        p[s][r] = __expf(st[s][r] - mnew);
        rsum += p[s][r];
      }
    rsum += __shfl_xor(rsum, 16);
    rsum += __shfl_xor(rsum, 32);
    lsum = lsum * scl + rsum;
#pragma unroll
    for (int t = 0; t < 16; ++t) {
      ot[t][0] *= scl; ot[t][1] *= scl; ot[t][2] *= scl; ot[t][3] *= scl;
    }

    // P -> bf16 -> wave-private LDS -> B-fragments (m-local contiguous)
    char* prow = plw + col * 128;
#pragma unroll
    for (int s = 0; s < 4; ++s)
#pragma unroll
      for (int h = 0; h < 2; ++h) {
        const unsigned int pk = (unsigned int)f2bf(p[s][2 * h]) |
                                ((unsigned int)f2bf(p[s][2 * h + 1]) << 16);
        *(unsigned int*)(prow + ((32 * s + 8 * q + 4 * h) ^ ksw)) = pk;
      }
    bf16x8 pf[2];
#pragma unroll
    for (int c = 0; c < 2; ++c)
      pf[c] = *(const bf16x8*)(prow + ((64 * c + 16 * q) ^ ksw));

    // O^T += V^T . P^T
#pragma unroll
    for (int c = 0; c < 2; ++c)
#pragma unroll
      for (int t = 0; t < 16; ++t) {
        const bf16x8 vf = *(const bf16x8*)((const char*)vt + (16 * t + col) * 128 +
                                           ((64 * c + 16 * q) ^ ksw));
        ot[t] = __builtin_amdgcn_mfma_f32_16x16x32_bf16(vf, pf[c], ot[t], 0, 0, 0);
      }
  }

  // normalize + transposed store via LDS (reuse vt as f32 [64][68])
  const float inv = 1.f / lsum;
  float* buf = (float*)vt;
  const int dl = tid >> 2, ns = (tid & 3) * 16;
#pragma unroll
  for (int rd = 0; rd < 4; ++rd) {
    __syncthreads();
#pragma unroll
    for (int tt = 0; tt < 4; ++tt) {
      const int t = 4 * rd + tt;
#pragma unroll
      for (int r = 0; r < 4; ++r)
        buf[(16 * tt + 4 * q + r) * 68 + 16 * w + col] = ot[t][r] * inv;
    }
    __syncthreads();
    float* dst = yT + ((size_t)(b * 256 + 64 * rd + dl)) * 4096 + n0 + ns;
    const float* sr = buf + dl * 68 + ns;
#pragma unroll
    for (int k = 0; k < 4; ++k)
      *(float4*)(dst + 4 * k) = make_float4(sr[4 * k], sr[4 * k + 1],
                                            sr[4 * k + 2], sr[4 * k + 3]);
  }
}

// ---------------------------------------------------------------------------
// Final W conv + bias + residual. K=128.
// out[b][o*2+gr][n] = sum_i W_w[o][i]*yT[2i+gr][n] + W_b[o] + x[...]
// ---------------------------------------------------------------------------
__global__ __launch_bounds__(256)
void k_gemm_final(const float* __restrict__ x,
                  const float* __restrict__ Ww, const float* __restrict__ Wb,
                  const float* __restrict__ ws, float* __restrict__ out) {
  const int nt = blockIdx.x, gq = blockIdx.y, b = blockIdx.z;
  const int gr = gq & 1, ob = (gq >> 1) * 128;
  const int n0 = nt * 64;
  const int tid = threadIdx.x;
  const int tx = tid & 15, ty = tid >> 4;

  __shared__ float a_s[16][68];
  __shared__ float w_s[16][128];

  float acc[4][8];
#pragma unroll
  for (int i = 0; i < 4; ++i)
#pragma unroll
    for (int j = 0; j < 8; ++j) acc[i][j] = 0.f;

  const int lkk = tid >> 4;
  const int lnn = (tid & 15) * 4;
  const int lo  = tid & 127;
  const int lkb = (tid >> 7) * 8;

  for (int kc = 0; kc < 128; kc += 16) {
    const float* ys = ws + F_YT + ((size_t)(b * 256 + 2 * (kc + lkk) + gr)) * 4096 + n0 + lnn;
    *(float4*)&a_s[lkk][lnn] = *(const float4*)ys;
    const float* wp = Ww + (size_t)(ob + lo) * 128 + kc + lkb;
    float4 w0 = *(const float4*)wp;
    float4 w1 = *(const float4*)(wp + 4);
    w_s[lkb + 0][lo] = w0.x; w_s[lkb + 1][lo] = w0.y;
    w_s[lkb + 2][lo] = w0.z; w_s[lkb + 3][lo] = w0.w;
    w_s[lkb + 4][lo] = w1.x; w_s[lkb + 5][lo] = w1.y;
    w_s[lkb + 6][lo] = w1.z; w_s[lkb + 7][lo] = w1.w;
    __syncthreads();
#pragma unroll
    for (int kk = 0; kk < 16; ++kk) {
      const float4 a4 = *(const float4*)&a_s[kk][4 * tx];
      const float4 b0 = *(const float4*)&w_s[kk][8 * ty];
      const float4 b1 = *(const float4*)&w_s[kk][8 * ty + 4];
      const float ar[4] = {a4.x, a4.y, a4.z, a4.w};
      const float br[8] = {b0.x, b0.y, b0.z, b0.w, b1.x, b1.y, b1.z, b1.w};
#pragma unroll
      for (int i = 0; i < 4; ++i)
#pragma unroll
        for (int j = 0; j < 8; ++j) acc[i][j] += ar[i] * br[j];
    }
    __syncthreads();
  }

  float bs[8];
#pragma unroll
  for (int j = 0; j < 8; ++j) bs[j] = Wb[ob + 8 * ty + j];

#pragma unroll
  for (int j = 0; j < 8; ++j) {
    const int o = ob + 8 * ty + j;
    const int ch = o * 2 + gr;
    const size_t off = ((size_t)(b * 512 + ch)) * 4096 + n0 + 4 * tx;
    const float4 xv = *(const float4*)(x + off);
    *(float4*)(out + off) = make_float4(acc[0][j] + bs[j] + xv.x,
                                        acc[1][j] + bs[j] + xv.y,
                                        acc[2][j] + bs[j] + xv.z,
                                        acc[3][j] + bs[j] + xv.w);
  }
}

extern "C" void kernel_launch(void* const* d_in, const int* in_sizes, int n_in,
                              void* d_out, int out_size, void* d_ws, size_t ws_size,
                              hipStream_t stream) {
  const float* x  = (const float*)d_in[0];
  const float* gw = (const float*)d_in[1];
  const float* gb = (const float*)d_in[2];
  const float* tw = (const float*)d_in[3];
  const float* tb = (const float*)d_in[4];
  const float* pw = (const float*)d_in[5];
  const float* pb = (const float*)d_in[6];
  const float* Ww = (const float*)d_in[7];
  const float* Wb = (const float*)d_in[8];
  float* out = (float*)d_out;
  float* ws  = (float*)d_ws;

  k_gemm_proj<<<dim3(64, 2, 8), 256, 0, stream>>>(x, tw, tb, pw, pb, ws);
  k_gemm_g<<<dim3(64, 2, 8), 256, 0, stream>>>(x, gw, gb, ws);
  k_pool_phi<<<4096, 256, 0, stream>>>(ws);
  k_pool_g<<<8192, 256, 0, stream>>>(ws);
  k_attn_mfma<<<dim3(64, 8), 256, 0, stream>>>(ws);
  k_gemm_final<<<dim3(64, 4, 8), 256, 0, stream>>>(x, Ww, Wb, ws, out);
}

// Round 5
// 197.737 us; speedup vs baseline: 3.5767x; 1.3959x over previous
//
#include <hip/hip_runtime.h>

// Workspace float offsets
#define F_XM    0u          // bf16 xm[8][4096][256]      -> 4,194,304 f
#define F_XG    4194304u    // bf16 xg[8][2][4096][256]   -> 8,388,608 f
#define F_Y     4194304u    // bf16 y[8][2][4096][128] aliases xg (dead after k_g)
#define F_TH    12582912u   // bf16 theta[8][4096][128]   -> 2,097,152 f
#define F_PHIB  14680064u   // bf16 phi[8][1024][128]     ->   524,288 f
#define F_GB    15204352u   // bf16 g[8][256][1024]       -> 1,048,576 f
// total 16,252,928 floats = 65.0 MB

typedef __attribute__((ext_vector_type(4))) float f32x4;
typedef __attribute__((ext_vector_type(8))) short bf16x8;

__device__ __forceinline__ unsigned short f2bf(float f) {
  union { unsigned int i; float f; } x; x.f = f;
  unsigned int r = x.i + 0x7fffu + ((x.i >> 16) & 1u);
  return (unsigned short)(r >> 16);
}
__device__ __forceinline__ unsigned int pk2(float a, float b) {
  return (unsigned int)f2bf(a) | ((unsigned int)f2bf(b) << 16);
}

// ---------------------------------------------------------------------------
// Prep: x f32 [b][512][4096] -> bf16 xm[b][n][256] (mean over group pair) and
// xg[b][gr][n][256] (K-contiguous layouts for the MFMA GEMMs).
// Block: [64 c][256 n] tile via swizzled LDS transpose.
// ---------------------------------------------------------------------------
__global__ __launch_bounds__(256)
void k_prep(const float* __restrict__ x, float* __restrict__ ws) {
  const int nt = blockIdx.x, ct = blockIdx.y, b = blockIdx.z;
  const int n0 = nt * 256, c0 = ct * 64;
  const int tid = threadIdx.x;
  __shared__ uint4 ldsb[4096];               // 64 KB: f32 [64 c][1024B] swz
  char* lds = (char*)ldsb;
  {
    const int c = tid >> 2;
    const int nch = (tid & 3) * 64;
    const float* src = x + ((size_t)(b * 512 + c0 + c)) * 4096 + n0 + nch;
    char* row = lds + c * 1024;
    const int sw = (c & 7) << 4;
    const int bb = nch * 4;
#pragma unroll
    for (int k = 0; k < 16; ++k)
      *(uint4*)(row + ((bb + 16 * k) ^ sw)) = ((const uint4*)src)[k];
  }
  __syncthreads();
  {
    const int n = tid;
    unsigned int u0[16], u1[16], um[16];
#pragma unroll
    for (int jc = 0; jc < 4; ++jc) {
      float v[16];
#pragma unroll
      for (int cc = 0; cc < 16; ++cc) {
        const int c = 16 * jc + cc;
        v[cc] = *(const float*)(lds + c * 1024 + ((n * 4) ^ ((c & 7) << 4)));
      }
#pragma unroll
      for (int s = 0; s < 4; ++s) {
        u0[4 * jc + s] = pk2(v[4 * s], v[4 * s + 2]);
        u1[4 * jc + s] = pk2(v[4 * s + 1], v[4 * s + 3]);
        um[4 * jc + s] = pk2(0.5f * (v[4 * s] + v[4 * s + 1]),
                             0.5f * (v[4 * s + 2] + v[4 * s + 3]));
      }
    }
    unsigned short* xm = (unsigned short*)(ws + F_XM);
    unsigned short* xg = (unsigned short*)(ws + F_XG);
    uint4* d0 = (uint4*)(xg + (((size_t)(b * 2 + 0) * 4096) + n0 + n) * 256 + (c0 >> 1));
    uint4* d1 = (uint4*)(xg + (((size_t)(b * 2 + 1) * 4096) + n0 + n) * 256 + (c0 >> 1));
    uint4* dm = (uint4*)(xm + ((size_t)(b * 4096) + n0 + n) * 256 + (c0 >> 1));
#pragma unroll
    for (int s = 0; s < 4; ++s) {
      d0[s] = make_uint4(u0[4 * s], u0[4 * s + 1], u0[4 * s + 2], u0[4 * s + 3]);
      d1[s] = make_uint4(u1[4 * s], u1[4 * s + 1], u1[4 * s + 2], u1[4 * s + 3]);
      dm[s] = make_uint4(um[4 * s], um[4 * s + 1], um[4 * s + 2], um[4 * s + 3]);
    }
  }
}

// ---------------------------------------------------------------------------
// MFMA GEMM core convention (verified by attn kernel):
//   D = A(16x32) . B(32x16): A-frag lane l = A[row=l&15][k-octet l>>4] (8 bf16
//   contig); B-frag lane l = B^T[col=l&15][k-octet l>>4]; D: row=(l>>4)*4+reg,
//   col=l&15. LDS tiles row-major K-contig, byte ^ ((row&7)<<4).
// ---------------------------------------------------------------------------

// theta & phi projections from xm (K=256). Out tile 128 o x 128 n, 4 waves.
// ot=0: theta[b][n][o] bf16 (LDS transpose). ot=1: pooled phiB[b][m][o] bf16.
__global__ __launch_bounds__(256)
void k_proj_mfma(const float* __restrict__ tw, const float* __restrict__ tb,
                 const float* __restrict__ pw, const float* __restrict__ pb,
                 float* __restrict__ ws) {
  const int nt = blockIdx.x, ot = blockIdx.y, b = blockIdx.z;
  const int n0 = nt * 128;
  const int tid = threadIdx.x;
  const int w = tid >> 6, lane = tid & 63, q = lane >> 4, col = lane & 15;
  const float* W = ot ? pw : tw;
  const float* bias = ot ? pb : tb;
  const unsigned short* xm = (const unsigned short*)(ws + F_XM);

  __shared__ uint4 ldsb[4096];               // 64 KB
  char* Ws = (char*)ldsb;                    // [128 o][128B] swz
  char* Xs = (char*)ldsb + 16384;            // [128 n][128B] swz

  f32x4 acc[2][8];
#pragma unroll
  for (int h = 0; h < 2; ++h)
#pragma unroll
    for (int j = 0; j < 8; ++j) acc[h][j] = (f32x4){0.f, 0.f, 0.f, 0.f};

  const int ro = tid >> 1, haf = tid & 1;
  for (int ks = 0; ks < 4; ++ks) {
    __syncthreads();
    {
      const float* src = W + (size_t)ro * 256 + ks * 64 + haf * 32;
      char* row = Ws + ro * 128;
      const int sw = (ro & 7) << 4;
#pragma unroll
      for (int jj = 0; jj < 4; ++jj) {
        float4 a = ((const float4*)src)[2 * jj];
        float4 c4 = ((const float4*)src)[2 * jj + 1];
        uint4 pk;
        pk.x = pk2(a.x, a.y);  pk.y = pk2(a.z, a.w);
        pk.z = pk2(c4.x, c4.y); pk.w = pk2(c4.z, c4.w);
        *(uint4*)(row + ((haf * 64 + 16 * jj) ^ sw)) = pk;
      }
    }
    {
      const unsigned short* src = xm + ((size_t)(b * 4096) + n0 + ro) * 256 + ks * 64 + haf * 32;
      char* row = Xs + ro * 128;
      const int sw = (ro & 7) << 4;
#pragma unroll
      for (int jj = 0; jj < 4; ++jj)
        *(uint4*)(row + ((haf * 64 + 16 * jj) ^ sw)) = ((const uint4*)src)[jj];
    }
    __syncthreads();
#pragma unroll
    for (int c = 0; c < 2; ++c) {
      bf16x8 af[2], bfr[8];
#pragma unroll
      for (int h = 0; h < 2; ++h) {
        const int r = 32 * w + 16 * h + col;
        af[h] = *(const bf16x8*)(Ws + r * 128 + ((64 * c + 16 * q) ^ ((r & 7) << 4)));
      }
#pragma unroll
      for (int j = 0; j < 8; ++j) {
        const int r = 16 * j + col;
        bfr[j] = *(const bf16x8*)(Xs + r * 128 + ((64 * c + 16 * q) ^ ((r & 7) << 4)));
      }
#pragma unroll
      for (int h = 0; h < 2; ++h)
#pragma unroll
        for (int j = 0; j < 8; ++j)
          acc[h][j] = __builtin_amdgcn_mfma_f32_16x16x32_bf16(af[h], bfr[j], acc[h][j], 0, 0, 0);
    }
  }

  float bs[2][4];
#pragma unroll
  for (int h = 0; h < 2; ++h) {
    const int o0 = 32 * w + 16 * h + 4 * q;
#pragma unroll
    for (int r = 0; r < 4; ++r) bs[h][r] = bias[o0 + r];
  }

  if (ot == 0) {
    char* trb = (char*)ldsb + 32768;         // [128 n][256B] swz, fresh region
#pragma unroll
    for (int h = 0; h < 2; ++h) {
      const int o0 = 32 * w + 16 * h + 4 * q;
#pragma unroll
      for (int j = 0; j < 8; ++j) {
        const int n = 16 * j + col;
        uint2 pkk = make_uint2(pk2(acc[h][j][0] + bs[h][0], acc[h][j][1] + bs[h][1]),
                               pk2(acc[h][j][2] + bs[h][2], acc[h][j][3] + bs[h][3]));
        *(uint2*)(trb + n * 256 + ((2 * o0) ^ ((n & 7) << 4))) = pkk;
      }
    }
    __syncthreads();
    {
      const int n = tid >> 1, h2 = tid & 1;
      unsigned short* dst = (unsigned short*)(ws + F_TH) + ((size_t)(b * 4096) + n0 + n) * 128 + h2 * 64;
      const char* row = trb + n * 256;
      const int sw = (n & 7) << 4;
#pragma unroll
      for (int k = 0; k < 8; ++k)
        ((uint4*)dst)[k] = *(const uint4*)(row + ((128 * h2 + 16 * k) ^ sw));
    }
  } else {
    // fused (1,2,2) max-pool -> phiB[b][m][o]. n-local = 16j+col; t-row=j>>1,
    // v = 16(j&1)+col. v-partner = shfl_xor(1); t-partner = acc[h][j+2].
    const int mb = (nt >> 3) * 256 + (nt & 7) * 32;
    unsigned short* phiB = (unsigned short*)(ws + F_PHIB);
#pragma unroll
    for (int h = 0; h < 2; ++h) {
      const int o0 = 32 * w + 16 * h + 4 * q;
#pragma unroll
      for (int jj = 0; jj < 4; ++jj) {
        const int j = (jj >> 1) * 4 + (jj & 1);   // {0,1,4,5}
        f32x4 pm;
#pragma unroll
        for (int r = 0; r < 4; ++r)
          pm[r] = fmaxf(acc[h][j][r], acc[h][j + 2][r]);
#pragma unroll
        for (int r = 0; r < 4; ++r)
          pm[r] = fmaxf(pm[r], __shfl_xor(pm[r], 1));
        if ((col & 1) == 0) {
          const int vp = 8 * (j & 1) + (col >> 1);
          const int m = mb + 16 * (j >> 2) + vp;
          uint2 pkk = make_uint2(pk2(pm[0] + bs[h][0], pm[1] + bs[h][1]),
                                 pk2(pm[2] + bs[h][2], pm[3] + bs[h][3]));
          *(uint2*)(phiB + ((size_t)(b * 1024) + m) * 128 + o0) = pkk;
        }
      }
    }
  }
}

// g projection from xg (per group, K=256), fused pool -> gB[b][d=2o+gr][m].
__global__ __launch_bounds__(256)
void k_g_mfma(const float* __restrict__ gw, const float* __restrict__ gb,
              float* __restrict__ ws) {
  const int nt = blockIdx.x, gr = blockIdx.y, b = blockIdx.z;
  const int n0 = nt * 128;
  const int tid = threadIdx.x;
  const int w = tid >> 6, lane = tid & 63, q = lane >> 4, col = lane & 15;
  const unsigned short* xg = (const unsigned short*)(ws + F_XG);

  __shared__ uint4 ldsb[4096];
  char* Ws = (char*)ldsb;
  char* Xs = (char*)ldsb + 16384;

  f32x4 acc[2][8];
#pragma unroll
  for (int h = 0; h < 2; ++h)
#pragma unroll
    for (int j = 0; j < 8; ++j) acc[h][j] = (f32x4){0.f, 0.f, 0.f, 0.f};

  const int ro = tid >> 1, haf = tid & 1;
  for (int ks = 0; ks < 4; ++ks) {
    __syncthreads();
    {
      const float* src = gw + (size_t)ro * 256 + ks * 64 + haf * 32;
      char* row = Ws + ro * 128;
      const int sw = (ro & 7) << 4;
#pragma unroll
      for (int jj = 0; jj < 4; ++jj) {
        float4 a = ((const float4*)src)[2 * jj];
        float4 c4 = ((const float4*)src)[2 * jj + 1];
        uint4 pk;
        pk.x = pk2(a.x, a.y);  pk.y = pk2(a.z, a.w);
        pk.z = pk2(c4.x, c4.y); pk.w = pk2(c4.z, c4.w);
        *(uint4*)(row + ((haf * 64 + 16 * jj) ^ sw)) = pk;
      }
    }
    {
      const unsigned short* src = xg + (((size_t)(b * 2 + gr)) * 4096 + n0 + ro) * 256 + ks * 64 + haf * 32;
      char* row = Xs + ro * 128;
      const int sw = (ro & 7) << 4;
#pragma unroll
      for (int jj = 0; jj < 4; ++jj)
        *(uint4*)(row + ((haf * 64 + 16 * jj) ^ sw)) = ((const uint4*)src)[jj];
    }
    __syncthreads();
#pragma unroll
    for (int c = 0; c < 2; ++c) {
      bf16x8 af[2], bfr[8];
#pragma unroll
      for (int h = 0; h < 2; ++h) {
        const int r = 32 * w + 16 * h + col;
        af[h] = *(const bf16x8*)(Ws + r * 128 + ((64 * c + 16 * q) ^ ((r & 7) << 4)));
      }
#pragma unroll
      for (int j = 0; j < 8; ++j) {
        const int r = 16 * j + col;
        bfr[j] = *(const bf16x8*)(Xs + r * 128 + ((64 * c + 16 * q) ^ ((r & 7) << 4)));
      }
#pragma unroll
      for (int h = 0; h < 2; ++h)
#pragma unroll
        for (int j = 0; j < 8; ++j)
          acc[h][j] = __builtin_amdgcn_mfma_f32_16x16x32_bf16(af[h], bfr[j], acc[h][j], 0, 0, 0);
    }
  }

  const int mb = (nt >> 3) * 256 + (nt & 7) * 32;
  char* pt = (char*)ldsb + 32768;            // [128 o][80B], fresh region
#pragma unroll
  for (int h = 0; h < 2; ++h) {
    const int o0 = 32 * w + 16 * h + 4 * q;
#pragma unroll
    for (int jj = 0; jj < 4; ++jj) {
      const int j = (jj >> 1) * 4 + (jj & 1);
      f32x4 pm;
#pragma unroll
      for (int r = 0; r < 4; ++r)
        pm[r] = fmaxf(acc[h][j][r], acc[h][j + 2][r]);
#pragma unroll
      for (int r = 0; r < 4; ++r)
        pm[r] = fmaxf(pm[r], __shfl_xor(pm[r], 1));
      if ((col & 1) == 0) {
        const int ml = 16 * (j >> 2) + 8 * (j & 1) + (col >> 1);
#pragma unroll
        for (int r = 0; r < 4; ++r)
          *(unsigned short*)(pt + (o0 + r) * 80 + ml * 2) = f2bf(pm[r] + gb[o0 + r]);
      }
    }
  }
  __syncthreads();
  if (tid < 128) {
    const int o = tid;
    const char* row = pt + o * 80;
    unsigned short* dst = (unsigned short*)(ws + F_GB) + ((size_t)(b * 256) + 2 * o + gr) * 1024 + mb;
#pragma unroll
    for (int k = 0; k < 4; ++k)
      ((uint4*)dst)[k] = *(const uint4*)(row + 16 * k);
  }
}

// ---------------------------------------------------------------------------
// MFMA flash attention (core unchanged from R4). Epilogue now emits
// y[b][gr][n][i] bf16 (gr = d&1, i = d>>1) for the final MFMA GEMM.
// ---------------------------------------------------------------------------
__global__ __launch_bounds__(256)
void k_attn_mfma(float* __restrict__ ws) {
  const int b = blockIdx.y;
  const int n0 = blockIdx.x * 64;
  const int tid = threadIdx.x;
  const int w = tid >> 6;
  const int lane = tid & 63;
  const int q = lane >> 4;
  const int col = lane & 15;
  const int ksw = (col & 7) << 4;

  __shared__ unsigned short kt[64 * 128];    // K tile [m][i]   16,384 B
  __shared__ unsigned short vt[256 * 64];    // V^T tile [d][m] 32,768 B
  __shared__ unsigned short pl[4 * 16 * 64]; // per-wave P       8,192 B

  const unsigned short* thetaB = (const unsigned short*)(ws + F_TH);
  const unsigned short* phiB   = (const unsigned short*)(ws + F_PHIB);
  const unsigned short* gB     = (const unsigned short*)(ws + F_GB);
  unsigned short* yB = (unsigned short*)(ws + F_Y);

  bf16x8 qf[4];
  {
    const unsigned short* qp = thetaB + ((size_t)(b * 4096 + n0 + 16 * w + col)) * 128 + 8 * q;
#pragma unroll
    for (int c = 0; c < 4; ++c)
      qf[c] = *(const bf16x8*)(qp + 32 * c);
  }

  f32x4 ot[16];
#pragma unroll
  for (int t = 0; t < 16; ++t) ot[t] = (f32x4){0.f, 0.f, 0.f, 0.f};
  float mrun = -1e30f, lsum = 0.f;

  char* plw = (char*)pl + w * 2048;

  for (int mt = 0; mt < 16; ++mt) {
    const int m0 = mt * 64;
    __syncthreads();
    {
      const int r = tid >> 2;
      const unsigned short* src = phiB + ((size_t)(b * 1024 + m0 + r)) * 128 + (tid & 3) * 32;
      char* drow = (char*)kt + r * 256;
      const int sw = (r & 7) << 4;
      const int b0 = (tid & 3) * 64;
#pragma unroll
      for (int k = 0; k < 4; ++k)
        *(uint4*)(drow + ((b0 + 16 * k) ^ sw)) = *(const uint4*)(src + 8 * k);
    }
    {
      const unsigned short* src = gB + ((size_t)(b * 256 + tid)) * 1024 + m0;
      char* drow = (char*)vt + tid * 128;
      const int sw = (tid & 7) << 4;
#pragma unroll
      for (int k = 0; k < 8; ++k)
        *(uint4*)(drow + ((16 * k) ^ sw)) = *(const uint4*)(src + 8 * k);
    }
    __syncthreads();

    f32x4 st[4];
#pragma unroll
    for (int s = 0; s < 4; ++s) st[s] = (f32x4){0.f, 0.f, 0.f, 0.f};
#pragma unroll
    for (int c = 0; c < 4; ++c) {
#pragma unroll
      for (int s = 0; s < 4; ++s) {
        const bf16x8 kf = *(const bf16x8*)((const char*)kt + (16 * s + col) * 256 +
                                           ((64 * c + 16 * q) ^ ksw));
        st[s] = __builtin_amdgcn_mfma_f32_16x16x32_bf16(kf, qf[c], st[s], 0, 0, 0);
      }
    }

    float pmax = -1e30f;
#pragma unroll
    for (int s = 0; s < 4; ++s)
#pragma unroll
      for (int r = 0; r < 4; ++r) pmax = fmaxf(pmax, st[s][r]);
    pmax = fmaxf(pmax, __shfl_xor(pmax, 16));
    pmax = fmaxf(pmax, __shfl_xor(pmax, 32));
    const float mnew = fmaxf(mrun, pmax);
    const float scl = __expf(mrun - mnew);
    mrun = mnew;
    float p[4][4];
    float rsum = 0.f;
#pragma unroll
    for (int s = 0; s < 4; ++s)
#pragma unroll
      for (int r = 0; r < 4; ++r) {
        p[s][r] = __expf(st[s][r] - mnew);
        rsum += p[s][r];
      }
    rsum += __shfl_xor(rsum, 16);
    rsum += __shfl_xor(rsum, 32);
    lsum = lsum * scl + rsum;
#pragma unroll
    for (int t = 0; t < 16; ++t) {
      ot[t][0] *= scl; ot[t][1] *= scl; ot[t][2] *= scl; ot[t][3] *= scl;
    }

    char* prow = plw + col * 128;
#pragma unroll
    for (int s = 0; s < 4; ++s)
#pragma unroll
      for (int h = 0; h < 2; ++h) {
        const unsigned int pk = (unsigned int)f2bf(p[s][2 * h]) |
                                ((unsigned int)f2bf(p[s][2 * h + 1]) << 16);
        *(unsigned int*)(prow + ((32 * s + 8 * q + 4 * h) ^ ksw)) = pk;
      }
    bf16x8 pf[2];
#pragma unroll
    for (int c = 0; c < 2; ++c)
      pf[c] = *(const bf16x8*)(prow + ((64 * c + 16 * q) ^ ksw));

#pragma unroll
    for (int c = 0; c < 2; ++c)
#pragma unroll
      for (int t = 0; t < 16; ++t) {
        const bf16x8 vf = *(const bf16x8*)((const char*)vt + (16 * t + col) * 128 +
                                           ((64 * c + 16 * q) ^ ksw));
        ot[t] = __builtin_amdgcn_mfma_f32_16x16x32_bf16(vf, pf[c], ot[t], 0, 0, 0);
      }
  }

  // epilogue: y[b][gr][n][i] bf16.  d = 16t+4q+r -> gr=r&1, i = 8t+2q+(r>>1)
  const float inv = 1.f / lsum;
  __syncthreads();
  char* yt = (char*)vt;                      // [128 rows (gr*64+nl)][256B] swz
  const int nl = 16 * w + col;
  const int swn = (nl & 7) << 4;
#pragma unroll
  for (int t = 0; t < 16; ++t) {
    const unsigned int w0 = pk2(ot[t][0] * inv, ot[t][2] * inv);
    const unsigned int w1 = pk2(ot[t][1] * inv, ot[t][3] * inv);
    const int bo = 16 * t + 4 * q;
    *(unsigned int*)(yt + nl * 256 + (bo ^ swn)) = w0;
    *(unsigned int*)(yt + (64 + nl) * 256 + (bo ^ swn)) = w1;
  }
  __syncthreads();
  {
    const int row = tid >> 1, h2 = tid & 1;
    const int gr = row >> 6, n = row & 63;
    unsigned short* dst = yB + (((size_t)(b * 2 + gr)) * 4096 + n0 + n) * 128 + h2 * 64;
    const char* srow = yt + row * 256;
    const int sw = (n & 7) << 4;
#pragma unroll
    for (int k = 0; k < 8; ++k)
      ((uint4*)dst)[k] = *(const uint4*)(srow + ((128 * h2 + 16 * k) ^ sw));
  }
}

// ---------------------------------------------------------------------------
// Final W conv (MFMA, K=128 per group) + bias + residual.
// out[b][2*(ob+o)+gr][n] = sum_i Ww[ob+o][i]*y[b][gr][n][i] + Wb + x
// ---------------------------------------------------------------------------
__global__ __launch_bounds__(256)
void k_final_mfma(const float* __restrict__ x,
                  const float* __restrict__ Ww, const float* __restrict__ Wb,
                  const float* __restrict__ ws, float* __restrict__ out) {
  const int nt = blockIdx.x, gq = blockIdx.y, b = blockIdx.z;
  const int gr = gq & 1, ob = (gq >> 1) * 128;
  const int n0 = nt * 128;
  const int tid = threadIdx.x;
  const int w = tid >> 6, lane = tid & 63, q = lane >> 4, col = lane & 15;
  const unsigned short* yb = (const unsigned short*)(ws + F_Y);

  __shared__ uint4 ldsb[4096];
  char* As = (char*)ldsb;
  char* Bs = (char*)ldsb + 16384;

  f32x4 acc[2][8];
#pragma unroll
  for (int h = 0; h < 2; ++h)
#pragma unroll
    for (int j = 0; j < 8; ++j) acc[h][j] = (f32x4){0.f, 0.f, 0.f, 0.f};

  const int ro = tid >> 1, haf = tid & 1;
  for (int ks = 0; ks < 2; ++ks) {
    __syncthreads();
    {
      const float* src = Ww + (size_t)(ob + ro) * 128 + ks * 64 + haf * 32;
      char* row = As + ro * 128;
      const int sw = (ro & 7) << 4;
#pragma unroll
      for (int jj = 0; jj < 4; ++jj) {
        float4 a = ((const float4*)src)[2 * jj];
        float4 c4 = ((const float4*)src)[2 * jj + 1];
        uint4 pk;
        pk.x = pk2(a.x, a.y);  pk.y = pk2(a.z, a.w);
        pk.z = pk2(c4.x, c4.y); pk.w = pk2(c4.z, c4.w);
        *(uint4*)(row + ((haf * 64 + 16 * jj) ^ sw)) = pk;
      }
    }
    {
      const unsigned short* src = yb + (((size_t)(b * 2 + gr)) * 4096 + n0 + ro) * 128 + ks * 64 + haf * 32;
      char* row = Bs + ro * 128;
      const int sw = (ro & 7) << 4;
#pragma unroll
      for (int jj = 0; jj < 4; ++jj)
        *(uint4*)(row + ((haf * 64 + 16 * jj) ^ sw)) = ((const uint4*)src)[jj];
    }
    __syncthreads();
#pragma unroll
    for (int c = 0; c < 2; ++c) {
      bf16x8 af[2], bfr[8];
#pragma unroll
      for (int h = 0; h < 2; ++h) {
        const int r = 32 * w + 16 * h + col;
        af[h] = *(const bf16x8*)(As + r * 128 + ((64 * c + 16 * q) ^ ((r & 7) << 4)));
      }
#pragma unroll
      for (int j = 0; j < 8; ++j) {
        const int r = 16 * j + col;
        bfr[j] = *(const bf16x8*)(Bs + r * 128 + ((64 * c + 16 * q) ^ ((r & 7) << 4)));
      }
#pragma unroll
      for (int h = 0; h < 2; ++h)
#pragma unroll
        for (int j = 0; j < 8; ++j)
          acc[h][j] = __builtin_amdgcn_mfma_f32_16x16x32_bf16(af[h], bfr[j], acc[h][j], 0, 0, 0);
    }
  }

  __syncthreads();                           // reuse whole LDS: f32 [128 o][512B]
  char* ft = (char*)ldsb;
#pragma unroll
  for (int h = 0; h < 2; ++h) {
    const int o0 = 32 * w + 16 * h + 4 * q;
#pragma unroll
    for (int j = 0; j < 8; ++j) {
      const int n = 16 * j + col;
#pragma unroll
      for (int r = 0; r < 4; ++r)
        *(float*)(ft + (o0 + r) * 512 + ((n * 4) ^ (((o0 + r) & 7) << 4))) = acc[h][j][r];
    }
  }
  __syncthreads();
  {
    const int o = tid >> 1, h2 = tid & 1;
    const float bsv = Wb[ob + o];
    const int ch = 2 * (ob + o) + gr;
    const size_t base = ((size_t)(b * 512 + ch)) * 4096 + n0 + h2 * 64;
    const char* row = ft + o * 512;
    const int sw = (o & 7) << 4;
#pragma unroll
    for (int k = 0; k < 16; ++k) {
      f32x4 v = *(const f32x4*)(row + ((256 * h2 + 16 * k) ^ sw));
      float4 xv = ((const float4*)(x + base))[k];
      ((float4*)(out + base))[k] = make_float4(v[0] + bsv + xv.x, v[1] + bsv + xv.y,
                                               v[2] + bsv + xv.z, v[3] + bsv + xv.w);
    }
  }
}

extern "C" void kernel_launch(void* const* d_in, const int* in_sizes, int n_in,
                              void* d_out, int out_size, void* d_ws, size_t ws_size,
                              hipStream_t stream) {
  const float* x  = (const float*)d_in[0];
  const float* gw = (const float*)d_in[1];
  const float* gb = (const float*)d_in[2];
  const float* tw = (const float*)d_in[3];
  const float* tb = (const float*)d_in[4];
  const float* pw = (const float*)d_in[5];
  const float* pb = (const float*)d_in[6];
  const float* Ww = (const float*)d_in[7];
  const float* Wb = (const float*)d_in[8];
  float* out = (float*)d_out;
  float* ws  = (float*)d_ws;

  k_prep<<<dim3(16, 8, 8), 256, 0, stream>>>(x, ws);
  k_proj_mfma<<<dim3(32, 2, 8), 256, 0, stream>>>(tw, tb, pw, pb, ws);
  k_g_mfma<<<dim3(32, 2, 8), 256, 0, stream>>>(gw, gb, ws);
  k_attn_mfma<<<dim3(64, 8), 256, 0, stream>>>(ws);
  k_final_mfma<<<dim3(32, 4, 8), 256, 0, stream>>>(x, Ww, Wb, ws, out);
}

// Round 6
// 191.286 us; speedup vs baseline: 3.6973x; 1.0337x over previous
//
#include <hip/hip_runtime.h>

// Workspace float offsets
#define F_XM    0u          // bf16 xm[8][4096][256]      -> 4,194,304 f
#define F_XG    4194304u    // bf16 xg[8][2][4096][256]   -> 8,388,608 f
#define F_Y     4194304u    // bf16 y[8][2][4096][128] aliases xg (dead after k_g)
#define F_TH    12582912u   // bf16 theta[8][4096][128]   -> 2,097,152 f
#define F_PHIB  14680064u   // bf16 phi[8][1024][128]     ->   524,288 f
#define F_GB    15204352u   // bf16 g[8][256][1024]       -> 1,048,576 f
// total 16,252,928 floats = 65.0 MB

typedef __attribute__((ext_vector_type(4))) float f32x4;
typedef __attribute__((ext_vector_type(8))) short bf16x8;

__device__ __forceinline__ unsigned short f2bf(float f) {
  union { unsigned int i; float f; } x; x.f = f;
  unsigned int r = x.i + 0x7fffu + ((x.i >> 16) & 1u);
  return (unsigned short)(r >> 16);
}
__device__ __forceinline__ unsigned int pk2(float a, float b) {
  return (unsigned int)f2bf(a) | ((unsigned int)f2bf(b) << 16);
}

// ---------------------------------------------------------------------------
// Prep: x f32 [b][512][4096] -> bf16 xm[b][n][256] (mean over group pair) and
// xg[b][gr][n][256] (K-contiguous layouts for the MFMA GEMMs).
// ---------------------------------------------------------------------------
__global__ __launch_bounds__(256)
void k_prep(const float* __restrict__ x, float* __restrict__ ws) {
  const int nt = blockIdx.x, ct = blockIdx.y, b = blockIdx.z;
  const int n0 = nt * 256, c0 = ct * 64;
  const int tid = threadIdx.x;
  __shared__ uint4 ldsb[4096];               // 64 KB: f32 [64 c][1024B] swz
  char* lds = (char*)ldsb;
  {
    const int c = tid >> 2;
    const int nch = (tid & 3) * 64;
    const float* src = x + ((size_t)(b * 512 + c0 + c)) * 4096 + n0 + nch;
    char* row = lds + c * 1024;
    const int sw = (c & 7) << 4;
    const int bb = nch * 4;
#pragma unroll
    for (int k = 0; k < 16; ++k)
      *(uint4*)(row + ((bb + 16 * k) ^ sw)) = ((const uint4*)src)[k];
  }
  __syncthreads();
  {
    const int n = tid;
    unsigned int u0[16], u1[16], um[16];
#pragma unroll
    for (int jc = 0; jc < 4; ++jc) {
      float v[16];
#pragma unroll
      for (int cc = 0; cc < 16; ++cc) {
        const int c = 16 * jc + cc;
        v[cc] = *(const float*)(lds + c * 1024 + ((n * 4) ^ ((c & 7) << 4)));
      }
#pragma unroll
      for (int s = 0; s < 4; ++s) {
        u0[4 * jc + s] = pk2(v[4 * s], v[4 * s + 2]);
        u1[4 * jc + s] = pk2(v[4 * s + 1], v[4 * s + 3]);
        um[4 * jc + s] = pk2(0.5f * (v[4 * s] + v[4 * s + 1]),
                             0.5f * (v[4 * s + 2] + v[4 * s + 3]));
      }
    }
    unsigned short* xm = (unsigned short*)(ws + F_XM);
    unsigned short* xg = (unsigned short*)(ws + F_XG);
    uint4* d0 = (uint4*)(xg + (((size_t)(b * 2 + 0) * 4096) + n0 + n) * 256 + (c0 >> 1));
    uint4* d1 = (uint4*)(xg + (((size_t)(b * 2 + 1) * 4096) + n0 + n) * 256 + (c0 >> 1));
    uint4* dm = (uint4*)(xm + ((size_t)(b * 4096) + n0 + n) * 256 + (c0 >> 1));
#pragma unroll
    for (int s = 0; s < 4; ++s) {
      d0[s] = make_uint4(u0[4 * s], u0[4 * s + 1], u0[4 * s + 2], u0[4 * s + 3]);
      d1[s] = make_uint4(u1[4 * s], u1[4 * s + 1], u1[4 * s + 2], u1[4 * s + 3]);
      dm[s] = make_uint4(um[4 * s], um[4 * s + 1], um[4 * s + 2], um[4 * s + 3]);
    }
  }
}

// ---------------------------------------------------------------------------
// theta & phi projections from xm (K=256). Out tile 128 o x 128 n, 4 waves.
// ot=0: theta[b][n][o] bf16 (LDS transpose). ot=1: pooled phiB[b][m][o] bf16.
// ---------------------------------------------------------------------------
__global__ __launch_bounds__(256)
void k_proj_mfma(const float* __restrict__ tw, const float* __restrict__ tb,
                 const float* __restrict__ pw, const float* __restrict__ pb,
                 float* __restrict__ ws) {
  const int nt = blockIdx.x, ot = blockIdx.y, b = blockIdx.z;
  const int n0 = nt * 128;
  const int tid = threadIdx.x;
  const int w = tid >> 6, lane = tid & 63, q = lane >> 4, col = lane & 15;
  const float* W = ot ? pw : tw;
  const float* bias = ot ? pb : tb;
  const unsigned short* xm = (const unsigned short*)(ws + F_XM);

  __shared__ uint4 ldsb[4096];               // 64 KB
  char* Ws = (char*)ldsb;                    // [128 o][128B] swz
  char* Xs = (char*)ldsb + 16384;            // [128 n][128B] swz

  f32x4 acc[2][8];
#pragma unroll
  for (int h = 0; h < 2; ++h)
#pragma unroll
    for (int j = 0; j < 8; ++j) acc[h][j] = (f32x4){0.f, 0.f, 0.f, 0.f};

  const int ro = tid >> 1, haf = tid & 1;
  for (int ks = 0; ks < 4; ++ks) {
    __syncthreads();
    {
      const float* src = W + (size_t)ro * 256 + ks * 64 + haf * 32;
      char* row = Ws + ro * 128;
      const int sw = (ro & 7) << 4;
#pragma unroll
      for (int jj = 0; jj < 4; ++jj) {
        float4 a = ((const float4*)src)[2 * jj];
        float4 c4 = ((const float4*)src)[2 * jj + 1];
        uint4 pk;
        pk.x = pk2(a.x, a.y);  pk.y = pk2(a.z, a.w);
        pk.z = pk2(c4.x, c4.y); pk.w = pk2(c4.z, c4.w);
        *(uint4*)(row + ((haf * 64 + 16 * jj) ^ sw)) = pk;
      }
    }
    {
      const unsigned short* src = xm + ((size_t)(b * 4096) + n0 + ro) * 256 + ks * 64 + haf * 32;
      char* row = Xs + ro * 128;
      const int sw = (ro & 7) << 4;
#pragma unroll
      for (int jj = 0; jj < 4; ++jj)
        *(uint4*)(row + ((haf * 64 + 16 * jj) ^ sw)) = ((const uint4*)src)[jj];
    }
    __syncthreads();
#pragma unroll
    for (int c = 0; c < 2; ++c) {
      bf16x8 af[2], bfr[8];
#pragma unroll
      for (int h = 0; h < 2; ++h) {
        const int r = 32 * w + 16 * h + col;
        af[h] = *(const bf16x8*)(Ws + r * 128 + ((64 * c + 16 * q) ^ ((r & 7) << 4)));
      }
#pragma unroll
      for (int j = 0; j < 8; ++j) {
        const int r = 16 * j + col;
        bfr[j] = *(const bf16x8*)(Xs + r * 128 + ((64 * c + 16 * q) ^ ((r & 7) << 4)));
      }
#pragma unroll
      for (int h = 0; h < 2; ++h)
#pragma unroll
        for (int j = 0; j < 8; ++j)
          acc[h][j] = __builtin_amdgcn_mfma_f32_16x16x32_bf16(af[h], bfr[j], acc[h][j], 0, 0, 0);
    }
  }

  float bs[2][4];
#pragma unroll
  for (int h = 0; h < 2; ++h) {
    const int o0 = 32 * w + 16 * h + 4 * q;
#pragma unroll
    for (int r = 0; r < 4; ++r) bs[h][r] = bias[o0 + r];
  }

  if (ot == 0) {
    char* trb = (char*)ldsb + 32768;         // [128 n][256B] swz, fresh region
#pragma unroll
    for (int h = 0; h < 2; ++h) {
      const int o0 = 32 * w + 16 * h + 4 * q;
#pragma unroll
      for (int j = 0; j < 8; ++j) {
        const int n = 16 * j + col;
        uint2 pkk = make_uint2(pk2(acc[h][j][0] + bs[h][0], acc[h][j][1] + bs[h][1]),
                               pk2(acc[h][j][2] + bs[h][2], acc[h][j][3] + bs[h][3]));
        *(uint2*)(trb + n * 256 + ((2 * o0) ^ ((n & 7) << 4))) = pkk;
      }
    }
    __syncthreads();
    {
      const int n = tid >> 1, h2 = tid & 1;
      unsigned short* dst = (unsigned short*)(ws + F_TH) + ((size_t)(b * 4096) + n0 + n) * 128 + h2 * 64;
      const char* row = trb + n * 256;
      const int sw = (n & 7) << 4;
#pragma unroll
      for (int k = 0; k < 8; ++k)
        ((uint4*)dst)[k] = *(const uint4*)(row + ((128 * h2 + 16 * k) ^ sw));
    }
  } else {
    const int mb = (nt >> 3) * 256 + (nt & 7) * 32;
    unsigned short* phiB = (unsigned short*)(ws + F_PHIB);
#pragma unroll
    for (int h = 0; h < 2; ++h) {
      const int o0 = 32 * w + 16 * h + 4 * q;
#pragma unroll
      for (int jj = 0; jj < 4; ++jj) {
        const int j = (jj >> 1) * 4 + (jj & 1);   // {0,1,4,5}
        f32x4 pm;
#pragma unroll
        for (int r = 0; r < 4; ++r)
          pm[r] = fmaxf(acc[h][j][r], acc[h][j + 2][r]);
#pragma unroll
        for (int r = 0; r < 4; ++r)
          pm[r] = fmaxf(pm[r], __shfl_xor(pm[r], 1));
        if ((col & 1) == 0) {
          const int vp = 8 * (j & 1) + (col >> 1);
          const int m = mb + 16 * (j >> 2) + vp;
          uint2 pkk = make_uint2(pk2(pm[0] + bs[h][0], pm[1] + bs[h][1]),
                                 pk2(pm[2] + bs[h][2], pm[3] + bs[h][3]));
          *(uint2*)(phiB + ((size_t)(b * 1024) + m) * 128 + o0) = pkk;
        }
      }
    }
  }
}

// ---------------------------------------------------------------------------
// g projection from xg (per group, K=256), fused pool -> gB[b][d=2o+gr][m].
// ---------------------------------------------------------------------------
__global__ __launch_bounds__(256)
void k_g_mfma(const float* __restrict__ gw, const float* __restrict__ gb,
              float* __restrict__ ws) {
  const int nt = blockIdx.x, gr = blockIdx.y, b = blockIdx.z;
  const int n0 = nt * 128;
  const int tid = threadIdx.x;
  const int w = tid >> 6, lane = tid & 63, q = lane >> 4, col = lane & 15;
  const unsigned short* xg = (const unsigned short*)(ws + F_XG);

  __shared__ uint4 ldsb[4096];
  char* Ws = (char*)ldsb;
  char* Xs = (char*)ldsb + 16384;

  f32x4 acc[2][8];
#pragma unroll
  for (int h = 0; h < 2; ++h)
#pragma unroll
    for (int j = 0; j < 8; ++j) acc[h][j] = (f32x4){0.f, 0.f, 0.f, 0.f};

  const int ro = tid >> 1, haf = tid & 1;
  for (int ks = 0; ks < 4; ++ks) {
    __syncthreads();
    {
      const float* src = gw + (size_t)ro * 256 + ks * 64 + haf * 32;
      char* row = Ws + ro * 128;
      const int sw = (ro & 7) << 4;
#pragma unroll
      for (int jj = 0; jj < 4; ++jj) {
        float4 a = ((const float4*)src)[2 * jj];
        float4 c4 = ((const float4*)src)[2 * jj + 1];
        uint4 pk;
        pk.x = pk2(a.x, a.y);  pk.y = pk2(a.z, a.w);
        pk.z = pk2(c4.x, c4.y); pk.w = pk2(c4.z, c4.w);
        *(uint4*)(row + ((haf * 64 + 16 * jj) ^ sw)) = pk;
      }
    }
    {
      const unsigned short* src = xg + (((size_t)(b * 2 + gr)) * 4096 + n0 + ro) * 256 + ks * 64 + haf * 32;
      char* row = Xs + ro * 128;
      const int sw = (ro & 7) << 4;
#pragma unroll
      for (int jj = 0; jj < 4; ++jj)
        *(uint4*)(row + ((haf * 64 + 16 * jj) ^ sw)) = ((const uint4*)src)[jj];
    }
    __syncthreads();
#pragma unroll
    for (int c = 0; c < 2; ++c) {
      bf16x8 af[2], bfr[8];
#pragma unroll
      for (int h = 0; h < 2; ++h) {
        const int r = 32 * w + 16 * h + col;
        af[h] = *(const bf16x8*)(Ws + r * 128 + ((64 * c + 16 * q) ^ ((r & 7) << 4)));
      }
#pragma unroll
      for (int j = 0; j < 8; ++j) {
        const int r = 16 * j + col;
        bfr[j] = *(const bf16x8*)(Xs + r * 128 + ((64 * c + 16 * q) ^ ((r & 7) << 4)));
      }
#pragma unroll
      for (int h = 0; h < 2; ++h)
#pragma unroll
        for (int j = 0; j < 8; ++j)
          acc[h][j] = __builtin_amdgcn_mfma_f32_16x16x32_bf16(af[h], bfr[j], acc[h][j], 0, 0, 0);
    }
  }

  const int mb = (nt >> 3) * 256 + (nt & 7) * 32;
  char* pt = (char*)ldsb + 32768;            // [128 o][80B], fresh region
#pragma unroll
  for (int h = 0; h < 2; ++h) {
    const int o0 = 32 * w + 16 * h + 4 * q;
#pragma unroll
    for (int jj = 0; jj < 4; ++jj) {
      const int j = (jj >> 1) * 4 + (jj & 1);
      f32x4 pm;
#pragma unroll
      for (int r = 0; r < 4; ++r)
        pm[r] = fmaxf(acc[h][j][r], acc[h][j + 2][r]);
#pragma unroll
      for (int r = 0; r < 4; ++r)
        pm[r] = fmaxf(pm[r], __shfl_xor(pm[r], 1));
      if ((col & 1) == 0) {
        const int ml = 16 * (j >> 2) + 8 * (j & 1) + (col >> 1);
#pragma unroll
        for (int r = 0; r < 4; ++r)
          *(unsigned short*)(pt + (o0 + r) * 80 + ml * 2) = f2bf(pm[r] + gb[o0 + r]);
      }
    }
  }
  __syncthreads();
  if (tid < 128) {
    const int o = tid;
    const char* row = pt + o * 80;
    unsigned short* dst = (unsigned short*)(ws + F_GB) + ((size_t)(b * 256) + 2 * o + gr) * 1024 + mb;
#pragma unroll
    for (int k = 0; k < 4; ++k)
      ((uint4*)dst)[k] = *(const uint4*)(row + 16 * k);
  }
}

// ---------------------------------------------------------------------------
// MFMA flash attention v3: 512 threads (8 waves), 128 n-rows/block,
// reg-prefetch (T14), defer-max (T13), setprio (T5), batch->XCD grid.
// ---------------------------------------------------------------------------
__global__ __launch_bounds__(512)
void k_attn_mfma(float* __restrict__ ws) {
  const int b = blockIdx.x;          // 8 batches -> 8 XCDs (round-robin)
  const int n0 = blockIdx.y * 128;
  const int tid = threadIdx.x;
  const int w = tid >> 6;
  const int lane = tid & 63;
  const int q = lane >> 4;
  const int col = lane & 15;
  const int ksw = (col & 7) << 4;

  __shared__ char lds[65536];
  char* kt = lds;                    // 16 KB: K [64 m][256B] swz
  char* vt = lds + 16384;            // 32 KB: V^T [256 d][128B] swz
  char* plw = lds + 49152 + w * 2048;// 16 KB: per-wave P

  const unsigned short* thetaB = (const unsigned short*)(ws + F_TH);
  const unsigned short* phiB   = (const unsigned short*)(ws + F_PHIB);
  const unsigned short* gB     = (const unsigned short*)(ws + F_GB);
  unsigned short* yB = (unsigned short*)(ws + F_Y);

  // staging geometry
  const int kr = tid >> 3, kc = (tid & 7) * 16;
  const int vr = tid >> 1, vc = (tid & 1) * 32;
  const unsigned short* kbase = phiB + ((size_t)(b * 1024 + kr)) * 128 + kc;
  const unsigned short* vbase = gB + ((size_t)(b * 256 + vr)) * 1024 + vc;
  char* kdst = kt + kr * 256;
  char* vdst = vt + vr * 128;
  const int ksw2 = (kr & 7) << 4, kb0 = (tid & 7) * 32;
  const int vsw = (vr & 7) << 4, vb0 = (tid & 1) * 64;

  bf16x8 qf[4];
  {
    const unsigned short* qp = thetaB + ((size_t)(b * 4096 + n0 + 16 * w + col)) * 128 + 8 * q;
#pragma unroll
    for (int c = 0; c < 4; ++c) qf[c] = *(const bf16x8*)(qp + 32 * c);
  }

  f32x4 ot[16];
#pragma unroll
  for (int t = 0; t < 16; ++t) ot[t] = (f32x4){0.f, 0.f, 0.f, 0.f};
  float mrun = -1e30f, lsum = 0.f;

  uint4 kreg[2], vreg[4];
  kreg[0] = ((const uint4*)kbase)[0];
  kreg[1] = ((const uint4*)kbase)[1];
#pragma unroll
  for (int k = 0; k < 4; ++k) vreg[k] = ((const uint4*)vbase)[k];

  for (int mt = 0; mt < 16; ++mt) {
    // write staged tile to LDS (implicit vmcnt wait)
    *(uint4*)(kdst + ((kb0 + 0) ^ ksw2)) = kreg[0];
    *(uint4*)(kdst + ((kb0 + 16) ^ ksw2)) = kreg[1];
#pragma unroll
    for (int k = 0; k < 4; ++k)
      *(uint4*)(vdst + ((vb0 + 16 * k) ^ vsw)) = vreg[k];
    __syncthreads();
    // issue next tile's loads -> latency hides under compute below
    if (mt < 15) {
      const int m1 = (mt + 1) * 64;
      const uint4* kp = (const uint4*)(kbase + (size_t)m1 * 128);
      kreg[0] = kp[0];
      kreg[1] = kp[1];
      const uint4* vp = (const uint4*)(vbase + m1);
#pragma unroll
      for (int k = 0; k < 4; ++k) vreg[k] = vp[k];
    }

    // S^T = K . Q^T
    f32x4 st[4];
#pragma unroll
    for (int s = 0; s < 4; ++s) st[s] = (f32x4){0.f, 0.f, 0.f, 0.f};
    __builtin_amdgcn_s_setprio(1);
#pragma unroll
    for (int c = 0; c < 4; ++c) {
#pragma unroll
      for (int s = 0; s < 4; ++s) {
        const bf16x8 kf = *(const bf16x8*)(kt + (16 * s + col) * 256 +
                                           ((64 * c + 16 * q) ^ ksw));
        st[s] = __builtin_amdgcn_mfma_f32_16x16x32_bf16(kf, qf[c], st[s], 0, 0, 0);
      }
    }
    __builtin_amdgcn_s_setprio(0);

    // online softmax with defer-max (threshold 8)
    float pmax = -1e30f;
#pragma unroll
    for (int s = 0; s < 4; ++s)
#pragma unroll
      for (int r = 0; r < 4; ++r) pmax = fmaxf(pmax, st[s][r]);
    pmax = fmaxf(pmax, __shfl_xor(pmax, 16));
    pmax = fmaxf(pmax, __shfl_xor(pmax, 32));
    if (!__all(pmax - mrun <= 8.f)) {
      const float mnew = fmaxf(mrun, pmax);
      const float scl = __expf(mrun - mnew);
      mrun = mnew;
      lsum *= scl;
#pragma unroll
      for (int t = 0; t < 16; ++t) {
        ot[t][0] *= scl; ot[t][1] *= scl; ot[t][2] *= scl; ot[t][3] *= scl;
      }
    }
    float rsum = 0.f;
#pragma unroll
    for (int s = 0; s < 4; ++s)
#pragma unroll
      for (int r = 0; r < 4; ++r) {
        st[s][r] = __expf(st[s][r] - mrun);   // p in-place
        rsum += st[s][r];
      }
    rsum += __shfl_xor(rsum, 16);
    rsum += __shfl_xor(rsum, 32);
    lsum += rsum;

    // P -> bf16 -> wave-private LDS -> B-fragments
    char* prow = plw + col * 128;
#pragma unroll
    for (int s = 0; s < 4; ++s)
#pragma unroll
      for (int h = 0; h < 2; ++h)
        *(unsigned int*)(prow + ((32 * s + 8 * q + 4 * h) ^ ksw)) =
            pk2(st[s][2 * h], st[s][2 * h + 1]);
    bf16x8 pf[2];
#pragma unroll
    for (int c = 0; c < 2; ++c)
      pf[c] = *(const bf16x8*)(prow + ((64 * c + 16 * q) ^ ksw));

    // O^T += V^T . P^T
    __builtin_amdgcn_s_setprio(1);
#pragma unroll
    for (int c = 0; c < 2; ++c)
#pragma unroll
      for (int t = 0; t < 16; ++t) {
        const bf16x8 vf = *(const bf16x8*)(vt + (16 * t + col) * 128 +
                                           ((64 * c + 16 * q) ^ ksw));
        ot[t] = __builtin_amdgcn_mfma_f32_16x16x32_bf16(vf, pf[c], ot[t], 0, 0, 0);
      }
    __builtin_amdgcn_s_setprio(0);
    __syncthreads();
  }

  // epilogue: y[b][gr][n][i] bf16. d = 16t+4q+r -> gr=r&1, i = 8t+2q+(r>>1)
  const float inv = 1.f / lsum;
  char* yt = lds;                    // [256 rows (gr*128+nl)][256B] swz
  const int nl = 16 * w + col;
  const int swn = (nl & 7) << 4;
#pragma unroll
  for (int t = 0; t < 16; ++t) {
    const unsigned int w0 = pk2(ot[t][0] * inv, ot[t][2] * inv);
    const unsigned int w1 = pk2(ot[t][1] * inv, ot[t][3] * inv);
    const int bo = 16 * t + 4 * q;
    *(unsigned int*)(yt + nl * 256 + (bo ^ swn)) = w0;
    *(unsigned int*)(yt + (128 + nl) * 256 + (bo ^ swn)) = w1;
  }
  __syncthreads();
  {
    const int row = tid >> 1, h2 = tid & 1;
    const int gr = row >> 7, n = row & 127;
    unsigned short* dst = yB + (((size_t)(b * 2 + gr)) * 4096 + n0 + n) * 128 + h2 * 64;
    const char* srow = yt + row * 256;
    const int sw = (n & 7) << 4;
#pragma unroll
    for (int k = 0; k < 8; ++k)
      ((uint4*)dst)[k] = *(const uint4*)(srow + ((128 * h2 + 16 * k) ^ sw));
  }
}

// ---------------------------------------------------------------------------
// Final W conv (MFMA, K=128 per group) + bias + residual.
// ---------------------------------------------------------------------------
__global__ __launch_bounds__(256)
void k_final_mfma(const float* __restrict__ x,
                  const float* __restrict__ Ww, const float* __restrict__ Wb,
                  const float* __restrict__ ws, float* __restrict__ out) {
  const int nt = blockIdx.x, gq = blockIdx.y, b = blockIdx.z;
  const int gr = gq & 1, ob = (gq >> 1) * 128;
  const int n0 = nt * 128;
  const int tid = threadIdx.x;
  const int w = tid >> 6, lane = tid & 63, q = lane >> 4, col = lane & 15;
  const unsigned short* yb = (const unsigned short*)(ws + F_Y);

  __shared__ uint4 ldsb[4096];
  char* As = (char*)ldsb;
  char* Bs = (char*)ldsb + 16384;

  f32x4 acc[2][8];
#pragma unroll
  for (int h = 0; h < 2; ++h)
#pragma unroll
    for (int j = 0; j < 8; ++j) acc[h][j] = (f32x4){0.f, 0.f, 0.f, 0.f};

  const int ro = tid >> 1, haf = tid & 1;
  for (int ks = 0; ks < 2; ++ks) {
    __syncthreads();
    {
      const float* src = Ww + (size_t)(ob + ro) * 128 + ks * 64 + haf * 32;
      char* row = As + ro * 128;
      const int sw = (ro & 7) << 4;
#pragma unroll
      for (int jj = 0; jj < 4; ++jj) {
        float4 a = ((const float4*)src)[2 * jj];
        float4 c4 = ((const float4*)src)[2 * jj + 1];
        uint4 pk;
        pk.x = pk2(a.x, a.y);  pk.y = pk2(a.z, a.w);
        pk.z = pk2(c4.x, c4.y); pk.w = pk2(c4.z, c4.w);
        *(uint4*)(row + ((haf * 64 + 16 * jj) ^ sw)) = pk;
      }
    }
    {
      const unsigned short* src = yb + (((size_t)(b * 2 + gr)) * 4096 + n0 + ro) * 128 + ks * 64 + haf * 32;
      char* row = Bs + ro * 128;
      const int sw = (ro & 7) << 4;
#pragma unroll
      for (int jj = 0; jj < 4; ++jj)
        *(uint4*)(row + ((haf * 64 + 16 * jj) ^ sw)) = ((const uint4*)src)[jj];
    }
    __syncthreads();
#pragma unroll
    for (int c = 0; c < 2; ++c) {
      bf16x8 af[2], bfr[8];
#pragma unroll
      for (int h = 0; h < 2; ++h) {
        const int r = 32 * w + 16 * h + col;
        af[h] = *(const bf16x8*)(As + r * 128 + ((64 * c + 16 * q) ^ ((r & 7) << 4)));
      }
#pragma unroll
      for (int j = 0; j < 8; ++j) {
        const int r = 16 * j + col;
        bfr[j] = *(const bf16x8*)(Bs + r * 128 + ((64 * c + 16 * q) ^ ((r & 7) << 4)));
      }
#pragma unroll
      for (int h = 0; h < 2; ++h)
#pragma unroll
        for (int j = 0; j < 8; ++j)
          acc[h][j] = __builtin_amdgcn_mfma_f32_16x16x32_bf16(af[h], bfr[j], acc[h][j], 0, 0, 0);
    }
  }

  __syncthreads();                           // reuse whole LDS: f32 [128 o][512B]
  char* ft = (char*)ldsb;
#pragma unroll
  for (int h = 0; h < 2; ++h) {
    const int o0 = 32 * w + 16 * h + 4 * q;
#pragma unroll
    for (int j = 0; j < 8; ++j) {
      const int n = 16 * j + col;
#pragma unroll
      for (int r = 0; r < 4; ++r)
        *(float*)(ft + (o0 + r) * 512 + ((n * 4) ^ (((o0 + r) & 7) << 4))) = acc[h][j][r];
    }
  }
  __syncthreads();
  {
    const int o = tid >> 1, h2 = tid & 1;
    const float bsv = Wb[ob + o];
    const int ch = 2 * (ob + o) + gr;
    const size_t base = ((size_t)(b * 512 + ch)) * 4096 + n0 + h2 * 64;
    const char* row = ft + o * 512;
    const int sw = (o & 7) << 4;
#pragma unroll
    for (int k = 0; k < 16; ++k) {
      f32x4 v = *(const f32x4*)(row + ((256 * h2 + 16 * k) ^ sw));
      float4 xv = ((const float4*)(x + base))[k];
      ((float4*)(out + base))[k] = make_float4(v[0] + bsv + xv.x, v[1] + bsv + xv.y,
                                               v[2] + bsv + xv.z, v[3] + bsv + xv.w);
    }
  }
}

extern "C" void kernel_launch(void* const* d_in, const int* in_sizes, int n_in,
                              void* d_out, int out_size, void* d_ws, size_t ws_size,
                              hipStream_t stream) {
  const float* x  = (const float*)d_in[0];
  const float* gw = (const float*)d_in[1];
  const float* gb = (const float*)d_in[2];
  const float* tw = (const float*)d_in[3];
  const float* tb = (const float*)d_in[4];
  const float* pw = (const float*)d_in[5];
  const float* pb = (const float*)d_in[6];
  const float* Ww = (const float*)d_in[7];
  const float* Wb = (const float*)d_in[8];
  float* out = (float*)d_out;
  float* ws  = (float*)d_ws;

  k_prep<<<dim3(16, 8, 8), 256, 0, stream>>>(x, ws);
  k_proj_mfma<<<dim3(32, 2, 8), 256, 0, stream>>>(tw, tb, pw, pb, ws);
  k_g_mfma<<<dim3(32, 2, 8), 256, 0, stream>>>(gw, gb, ws);
  k_attn_mfma<<<dim3(8, 32), 512, 0, stream>>>(ws);
  k_final_mfma<<<dim3(32, 4, 8), 256, 0, stream>>>(x, Ww, Wb, ws, out);
}